// Round 12
// baseline (585.501 us; speedup 1.0000x reference)
//
#include <hip/hip_runtime.h>
#include <math.h>

#define G_ 512
#define N_ 512
#define NN_ (G_*N_)
#define EG_ 8192
#define CIN_ 128
#define HID_ 32
#define K_ 20
#define LAT_ 65
#define NSTRIPE 4
#define SW 8          // channels per stripe

// relative tie window: ~1.5 ulp of fp32 (2^-23 = 1.19e-7)
#define EPS_REL 1.8e-7f

// ---------------- CSR build v2: atomic count/place + per-bin sort ----------
__global__ __launch_bounds__(512) void csr2_kernel(const int* __restrict__ src,
                                                   const int* __restrict__ dst,
                                                   unsigned short* __restrict__ srcl,
                                                   int* __restrict__ gstart,
                                                   double* __restrict__ disd) {
    __shared__ int cnt[N_];
    __shared__ int startv[N_];
    __shared__ int tmpv[N_];
    __shared__ int cursor[N_];
    __shared__ unsigned short binE[EG_];
    int g = blockIdx.x, tid = threadIdx.x;
    const int* ds = dst + (size_t)g * EG_;
    const int* ss = src + (size_t)g * EG_;
    int nb = g * N_;

    cnt[tid] = 0;
    __syncthreads();
    for (int e = tid; e < EG_; e += 512) atomicAdd(&cnt[ds[e] - nb], 1);
    __syncthreads();

    startv[tid] = cnt[tid];
    __syncthreads();
    for (int off = 1; off < N_; off <<= 1) {
        tmpv[tid] = startv[tid] + (tid >= off ? startv[tid - off] : 0);
        __syncthreads();
        startv[tid] = tmpv[tid];
        __syncthreads();
    }

    int excl = startv[tid] - cnt[tid];
    cursor[tid] = excl;
    gstart[g * (N_ + 1) + tid] = excl;
    if (tid == 0) gstart[g * (N_ + 1) + N_] = EG_;
    disd[nb + tid] = 1.0 / sqrt((double)(cnt[tid] + 1));
    __syncthreads();

    for (int e = tid; e < EG_; e += 512) {
        int d = ds[e] - nb;
        int slot = atomicAdd(&cursor[d], 1);
        binE[slot] = (unsigned short)e;
    }
    __syncthreads();

    {
        int n = cnt[tid];
        for (int i = 1; i < n; ++i) {
            unsigned short key = binE[excl + i];
            int j = i - 1;
            while (j >= 0 && binE[excl + j] > key) {
                binE[excl + j + 1] = binE[excl + j];
                --j;
            }
            binE[excl + j + 1] = key;
        }
    }
    __syncthreads();

    for (int i = tid; i < EG_; i += 512) {
        int e = binE[i];
        srcl[(size_t)g * EG_ + i] = (unsigned short)(ss[e] - nb);
    }
}

// ---------------- matmul: h[n][o] = sum_c x[n][c]*W[c][o], fp64 acc --------
// 64 nodes/block, 512 threads: thread = (q = tid>>5 -> 4 nodes, o = tid&31).
// Writes h in stripe-major layout: h[(o/8)*NN + n][8] + o%8.
template <int CI>
__global__ __launch_bounds__(512) void mm_kernel(const float* __restrict__ xin,
                                                 const float* __restrict__ W,
                                                 double* __restrict__ h) {
    __shared__ double sx[64][CI + 1];    // CI=128: 66 KB
    __shared__ double sWd[CI][HID_];     // CI=128: 32 KB
    int tid = threadIdx.x;
    for (int i = tid; i < CI * HID_; i += 512) sWd[i / HID_][i % HID_] = (double)W[i];
    size_t base = (size_t)blockIdx.x * 64;
    const float* xsrc = xin + base * CI;
    for (int i = tid; i < 64 * CI; i += 512) sx[i / CI][i % CI] = (double)xsrc[i];
    __syncthreads();

    int o = tid & 31, q = tid >> 5;      // 16 q-groups x 4 nodes
    int n0 = q * 4;
    double acc[4];
#pragma unroll
    for (int j = 0; j < 4; ++j) acc[j] = 0.0;
    for (int c = 0; c < CI; ++c) {
        double w = sWd[c][o];
#pragma unroll
        for (int j = 0; j < 4; ++j)
            acc[j] = fma(sx[n0 + j][c], w, acc[j]);
    }
    size_t sb = (size_t)(o >> 3) * NN_;
    int oc = o & 7;
#pragma unroll
    for (int j = 0; j < 4; ++j)
        h[(sb + base + n0 + j) * SW + oc] = acc[j];
}

// ---------------- aggregation: stripe-split, hd2 pre-scaled in LDS ---------
// Block (g, st) handles 8 channels. hd2[s] = h[s]*dis[s] (bit-identical to
// per-edge multiply). Edge loop = pure fp64 add chain, 8 nodes interleaved.
__global__ __launch_bounds__(512) void agg_kernel(const double* __restrict__ h,
                                                  const unsigned short* __restrict__ srcl,
                                                  const int* __restrict__ gstart,
                                                  const double* __restrict__ disd,
                                                  const float* __restrict__ bias,
                                                  float* __restrict__ xoutf) {
    __shared__ double hd2[N_ * 9];          // padded [512][9] = 36.9 KB
    __shared__ unsigned short ssrc[EG_];    // 16 KB
    __shared__ int sstart[N_ + 1];
    __shared__ double sdis[N_];             // 4 KB
    int g = blockIdx.x, st = blockIdx.y, tid = threadIdx.x;
    size_t nbase = (size_t)g * N_;

    for (int i = tid; i < EG_; i += 512) ssrc[i] = srcl[(size_t)g * EG_ + i];
    for (int i = tid; i <= N_; i += 512) sstart[i] = gstart[g * (N_ + 1) + i];
    sdis[tid] = disd[nbase + tid];
    __syncthreads();

    const double* hraw = h + ((size_t)st * NN_ + nbase) * SW;
    for (int i = tid; i < N_ * SW; i += 512)
        hd2[(i >> 3) * 9 + (i & 7)] = hraw[i] * sdis[i >> 3];
    __syncthreads();

    int oc = tid & 7, grp = tid >> 3;   // 64 node-groups x 8 channels
    double b = (double)bias[st * SW + oc];

    int e0[8], e1[8];
    double a[8];
    int mx = 0;
#pragma unroll
    for (int j = 0; j < 8; ++j) {
        int n = grp + j * 64;
        e0[j] = sstart[n];
        e1[j] = sstart[n + 1];
        a[j] = 0.0;
        int d = e1[j] - e0[j];
        mx = d > mx ? d : mx;
    }
    for (int t = 0; t < mx; ++t) {
#pragma unroll
        for (int j = 0; j < 8; ++j) {
            int idx = e0[j] + t;
            if (idx < e1[j]) {
                int s = ssrc[idx];
                a[j] += hd2[s * 9 + oc];
            }
        }
    }
#pragma unroll
    for (int j = 0; j < 8; ++j) {
        int n = grp + j * 64;
        double dn = sdis[n];
        double v = a[j] * dn + hd2[n * 9 + oc] * dn + b;
        xoutf[(nbase + n) * HID_ + st * SW + oc] = tanhf((float)v);
    }
}

// ---------------- layer 3 (32 -> 1): fp32 key = round(fp64 tanh) -----------
__global__ __launch_bounds__(512) void gcn3_kernel(const float* __restrict__ xin,
                                                   const float* __restrict__ W2,
                                                   const float* __restrict__ b2,
                                                   const unsigned short* __restrict__ srcl,
                                                   const int* __restrict__ gstart,
                                                   const double* __restrict__ disd,
                                                   float* __restrict__ x3f) {
    __shared__ double h1[N_];
    __shared__ unsigned short ssrc[EG_];
    __shared__ int sstart[N_ + 1];
    __shared__ double sdis[N_];
    int g = blockIdx.x, tid = threadIdx.x;
    size_t nbase = (size_t)g * N_;

    for (int i = tid; i < EG_; i += 512) ssrc[i] = srcl[(size_t)g * EG_ + i];
    for (int i = tid; i <= N_; i += 512) sstart[i] = gstart[g * (N_ + 1) + i];
    int n = tid;
    {
        double a = 0.0;
#pragma unroll
        for (int c = 0; c < HID_; ++c)
            a = fma((double)xin[(nbase + n) * HID_ + c], (double)W2[c], a);
        h1[n] = a;
        sdis[n] = disd[nbase + n];
    }
    __syncthreads();

    int e0 = sstart[n], e1 = sstart[n + 1];
    double a = 0.0;
    for (int e = e0; e < e1; ++e) {
        int s = ssrc[e];
        a += h1[s] * sdis[s];
    }
    double dn = sdis[n];
    double v = a * dn + h1[n] * dn * dn + (double)b2[0];
    x3f[nbase + n] = (float)tanh(v);   // fp32 rank key AND feature value
}

// ---------------- per-graph head: fp32 keys, ulp-window tie -> index -------
__global__ __launch_bounds__(256) void head_kernel(const float* __restrict__ x1,
                                                   const float* __restrict__ x2,
                                                   const float* __restrict__ x3f,
                                                   const float* __restrict__ c1w,
                                                   const float* __restrict__ c1b,
                                                   const float* __restrict__ c2w,
                                                   const float* __restrict__ c2b,
                                                   const float* __restrict__ l1w,
                                                   const float* __restrict__ l1b,
                                                   const float* __restrict__ l2w,
                                                   const float* __restrict__ l2b,
                                                   float* __restrict__ out) {
    int g = blockIdx.x;
    size_t nbase = (size_t)g * N_;
    __shared__ float sv[N_];
    __shared__ int   topk[K_];
    __shared__ float pooled[K_][LAT_];
    __shared__ float c1[16][K_];
    __shared__ float mp[16][10];
    __shared__ float c2[32 * 6];
    __shared__ float l1[128];

    for (int i = threadIdx.x; i < K_; i += 256) topk[i] = i;  // fallback
    for (int i = threadIdx.x; i < N_; i += 256) sv[i] = x3f[nbase + i];
    __syncthreads();

    // top-K descending on fp32 keys; pairs within ~1.5 ulp (relative) are
    // np-fp32 ties -> stable order (lower index first).
    for (int i = threadIdx.x; i < N_; i += 256) {
        float v = sv[i];
        int rank = 0;
        for (int j = 0; j < N_; ++j) {
            float u = sv[j];
            float mag = fmaxf(fabsf(u), fabsf(v));
            bool tie = fabsf(u - v) <= EPS_REL * mag;
            bool beats = tie ? (j < i) : (u > v);
            rank += beats;
        }
        if (rank < K_) topk[rank] = i;
    }
    __syncthreads();

    for (int i = threadIdx.x; i < K_ * LAT_; i += 256) {
        int k = i / LAT_, c = i % LAT_;
        int node = topk[k];
        float f;
        if (c < HID_)            f = x1[(nbase + node) * HID_ + c];
        else if (c < 2 * HID_)   f = x2[(nbase + node) * HID_ + (c - HID_)];
        else                     f = sv[node];
        pooled[k][c] = f;
    }
    __syncthreads();

    for (int i = threadIdx.x; i < 16 * K_; i += 256) {
        int o = i / K_, k = i % K_;
        float acc = c1b[o];
        for (int c = 0; c < LAT_; ++c) acc += pooled[k][c] * c1w[o * LAT_ + c];
        c1[o][k] = fmaxf(acc, 0.f);
    }
    __syncthreads();

    for (int i = threadIdx.x; i < 160; i += 256) {
        int o = i / 10, t = i % 10;
        mp[o][t] = fmaxf(c1[o][2 * t], c1[o][2 * t + 1]);
    }
    __syncthreads();

    for (int i = threadIdx.x; i < 192; i += 256) {
        int o = i / 6, t = i % 6;
        float acc = c2b[o];
        for (int ic = 0; ic < 16; ++ic)
#pragma unroll
            for (int j = 0; j < 5; ++j)
                acc += mp[ic][t + j] * c2w[(o * 16 + ic) * 5 + j];
        c2[o * 6 + t] = fmaxf(acc, 0.f);
    }
    __syncthreads();

    for (int i = threadIdx.x; i < 128; i += 256) {
        float acc = l1b[i];
        for (int c = 0; c < 192; ++c) acc += c2[c] * l1w[c * 128 + i];
        l1[i] = fmaxf(acc, 0.f);
    }
    __syncthreads();

    for (int i = threadIdx.x; i < 2; i += 256) {
        float acc = l2b[i];
        for (int c = 0; c < 128; ++c) acc += l1[c] * l2w[c * 2 + i];
        out[g * 2 + i] = acc;
    }
}

extern "C" void kernel_launch(void* const* d_in, const int* in_sizes, int n_in,
                              void* d_out, int out_size, void* d_ws, size_t ws_size,
                              hipStream_t stream) {
    const float* x   = (const float*)d_in[0];
    const int*   ei  = (const int*)d_in[1];
    const float* W0  = (const float*)d_in[3];
    const float* b0  = (const float*)d_in[4];
    const float* W1  = (const float*)d_in[5];
    const float* b1  = (const float*)d_in[6];
    const float* W2  = (const float*)d_in[7];
    const float* b2  = (const float*)d_in[8];
    const float* c1w = (const float*)d_in[9];
    const float* c1b = (const float*)d_in[10];
    const float* c2w = (const float*)d_in[11];
    const float* c2b = (const float*)d_in[12];
    const float* l1w = (const float*)d_in[13];
    const float* l1b = (const float*)d_in[14];
    const float* l2w = (const float*)d_in[15];
    const float* l2b = (const float*)d_in[16];

    const int* src = ei;
    const int* dst = ei + (size_t)G_ * EG_;

    char* wsb = (char*)d_ws;
    double* h64  = (double*)wsb;                 wsb += (size_t)NN_ * HID_ * 8;     // 64 MiB (stripe-major)
    unsigned short* srcl = (unsigned short*)wsb; wsb += (size_t)G_ * EG_ * 2;       // 8 MiB
    int* gstart = (int*)wsb;                     wsb += (size_t)G_ * (N_ + 1) * 4;  // 1 MiB
    double* disd = (double*)wsb;                 wsb += (size_t)NN_ * 8;            // 2 MiB
    float*  x3f  = (float*)wsb;                  wsb += (size_t)NN_ * 4;            // 1 MiB
    float*  x1f  = (float*)wsb;                  wsb += (size_t)NN_ * HID_ * 4;     // 32 MiB
    float*  x2f  = (float*)wsb;                  wsb += (size_t)NN_ * HID_ * 4;     // 32 MiB

    dim3 agrid(G_, NSTRIPE);
    csr2_kernel<<<G_, 512, 0, stream>>>(src, dst, srcl, gstart, disd);
    mm_kernel<CIN_><<<NN_ / 64, 512, 0, stream>>>(x, W0, h64);
    agg_kernel<<<agrid, 512, 0, stream>>>(h64, srcl, gstart, disd, b0, x1f);
    mm_kernel<HID_><<<NN_ / 64, 512, 0, stream>>>(x1f, W1, h64);
    agg_kernel<<<agrid, 512, 0, stream>>>(h64, srcl, gstart, disd, b1, x2f);
    gcn3_kernel<<<G_, 512, 0, stream>>>(x2f, W2, b2, srcl, gstart, disd, x3f);
    head_kernel<<<G_, 256, 0, stream>>>(x1f, x2f, x3f, c1w, c1b, c2w, c2b,
                                        l1w, l1b, l2w, l2b, (float*)d_out);
}

// Round 13
// 442.724 us; speedup vs baseline: 1.3225x; 1.3225x over previous
//
#include <hip/hip_runtime.h>
#include <math.h>

#define G_ 512
#define N_ 512
#define NN_ (G_*N_)
#define EG_ 8192
#define CIN_ 128
#define HID_ 32
#define K_ 20
#define LAT_ 65
#define NSTRIPE 4
#define SW 8          // channels per stripe

// relative tie window: ~1.5 ulp of fp32 (2^-23 = 1.19e-7)
#define EPS_REL 1.8e-7f

// ---------------- CSR build v2: atomic count/place + per-bin sort ----------
__global__ __launch_bounds__(512) void csr2_kernel(const int* __restrict__ src,
                                                   const int* __restrict__ dst,
                                                   unsigned short* __restrict__ srcl,
                                                   int* __restrict__ gstart,
                                                   double* __restrict__ disd) {
    __shared__ int cnt[N_];
    __shared__ int startv[N_];
    __shared__ int tmpv[N_];
    __shared__ int cursor[N_];
    __shared__ unsigned short binE[EG_];
    int g = blockIdx.x, tid = threadIdx.x;
    const int* ds = dst + (size_t)g * EG_;
    const int* ss = src + (size_t)g * EG_;
    int nb = g * N_;

    cnt[tid] = 0;
    __syncthreads();
    for (int e = tid; e < EG_; e += 512) atomicAdd(&cnt[ds[e] - nb], 1);
    __syncthreads();

    startv[tid] = cnt[tid];
    __syncthreads();
    for (int off = 1; off < N_; off <<= 1) {
        tmpv[tid] = startv[tid] + (tid >= off ? startv[tid - off] : 0);
        __syncthreads();
        startv[tid] = tmpv[tid];
        __syncthreads();
    }

    int excl = startv[tid] - cnt[tid];
    cursor[tid] = excl;
    gstart[g * (N_ + 1) + tid] = excl;
    if (tid == 0) gstart[g * (N_ + 1) + N_] = EG_;
    disd[nb + tid] = 1.0 / sqrt((double)(cnt[tid] + 1));
    __syncthreads();

    for (int e = tid; e < EG_; e += 512) {
        int d = ds[e] - nb;
        int slot = atomicAdd(&cursor[d], 1);
        binE[slot] = (unsigned short)e;
    }
    __syncthreads();

    {
        int n = cnt[tid];
        for (int i = 1; i < n; ++i) {
            unsigned short key = binE[excl + i];
            int j = i - 1;
            while (j >= 0 && binE[excl + j] > key) {
                binE[excl + j + 1] = binE[excl + j];
                --j;
            }
            binE[excl + j + 1] = key;
        }
    }
    __syncthreads();

    for (int i = tid; i < EG_; i += 512) {
        int e = binE[i];
        srcl[(size_t)g * EG_ + i] = (unsigned short)(ss[e] - nb);
    }
}

// ---------------- matmul: h[n][o] = sum_c x[n][c]*W[c][o], fp64 acc --------
// 64 nodes/block, 256 threads: thread = (q = tid>>5 -> 8 nodes, o = tid&31).
// c unrolled by 4, sx read as float4; fma applied c-ascending (bit-identical).
// Writes h stripe-major: h[((o/8)*NN + n)*8 + o%8].
template <int CI>
__global__ __launch_bounds__(256) void mm_kernel(const float* __restrict__ xin,
                                                 const float* __restrict__ W,
                                                 double* __restrict__ h) {
    __shared__ float sx[64][CI];         // CI=128: 32 KB
    __shared__ double sWd[CI][HID_];     // CI=128: 32 KB
    int tid = threadIdx.x;
    for (int i = tid; i < CI * HID_; i += 256) sWd[i / HID_][i % HID_] = (double)W[i];
    size_t base = (size_t)blockIdx.x * 64;
    const float4* xsrc = (const float4*)(xin + base * CI);
    float4* dst4 = (float4*)&sx[0][0];
    for (int i = tid; i < 64 * CI / 4; i += 256) dst4[i] = xsrc[i];
    __syncthreads();

    int o = tid & 31, q = tid >> 5;
    int n0 = q * 8;
    double acc[8];
#pragma unroll
    for (int j = 0; j < 8; ++j) acc[j] = 0.0;
    for (int c = 0; c < CI; c += 4) {
        double w0 = sWd[c][o], w1 = sWd[c + 1][o],
               w2 = sWd[c + 2][o], w3 = sWd[c + 3][o];
#pragma unroll
        for (int j = 0; j < 8; ++j) {
            float4 v = *(const float4*)&sx[n0 + j][c];
            acc[j] = fma((double)v.x, w0, acc[j]);
            acc[j] = fma((double)v.y, w1, acc[j]);
            acc[j] = fma((double)v.z, w2, acc[j]);
            acc[j] = fma((double)v.w, w3, acc[j]);
        }
    }
    size_t sb = (size_t)(o >> 3) * NN_;
    int oc = o & 7;
#pragma unroll
    for (int j = 0; j < 8; ++j)
        h[(sb + base + n0 + j) * SW + oc] = acc[j];
}

// ---------------- aggregation: stripe-split, hd2 pre-scaled in LDS ---------
__global__ __launch_bounds__(512) void agg_kernel(const double* __restrict__ h,
                                                  const unsigned short* __restrict__ srcl,
                                                  const int* __restrict__ gstart,
                                                  const double* __restrict__ disd,
                                                  const float* __restrict__ bias,
                                                  float* __restrict__ xoutf) {
    __shared__ double hd2[N_ * 9];          // padded [512][9] = 36.9 KB
    __shared__ unsigned short ssrc[EG_];    // 16 KB
    __shared__ int sstart[N_ + 1];
    __shared__ double sdis[N_];             // 4 KB
    int g = blockIdx.x, st = blockIdx.y, tid = threadIdx.x;
    size_t nbase = (size_t)g * N_;

    for (int i = tid; i < EG_; i += 512) ssrc[i] = srcl[(size_t)g * EG_ + i];
    for (int i = tid; i <= N_; i += 512) sstart[i] = gstart[g * (N_ + 1) + i];
    sdis[tid] = disd[nbase + tid];
    __syncthreads();

    const double* hraw = h + ((size_t)st * NN_ + nbase) * SW;
    for (int i = tid; i < N_ * SW; i += 512)
        hd2[(i >> 3) * 9 + (i & 7)] = hraw[i] * sdis[i >> 3];
    __syncthreads();

    int oc = tid & 7, grp = tid >> 3;   // 64 node-groups x 8 channels
    double b = (double)bias[st * SW + oc];

    int e0[8], e1[8];
    double a[8];
    int mx = 0;
#pragma unroll
    for (int j = 0; j < 8; ++j) {
        int n = grp + j * 64;
        e0[j] = sstart[n];
        e1[j] = sstart[n + 1];
        a[j] = 0.0;
        int d = e1[j] - e0[j];
        mx = d > mx ? d : mx;
    }
    for (int t = 0; t < mx; ++t) {
#pragma unroll
        for (int j = 0; j < 8; ++j) {
            int idx = e0[j] + t;
            if (idx < e1[j]) {
                int s = ssrc[idx];
                a[j] += hd2[s * 9 + oc];
            }
        }
    }
#pragma unroll
    for (int j = 0; j < 8; ++j) {
        int n = grp + j * 64;
        double dn = sdis[n];
        double v = a[j] * dn + hd2[n * 9 + oc] * dn + b;
        xoutf[(nbase + n) * HID_ + st * SW + oc] = tanhf((float)v);
    }
}

// ---------------- layer 3 (32 -> 1): fp32 key = round(fp64 tanh) -----------
__global__ __launch_bounds__(512) void gcn3_kernel(const float* __restrict__ xin,
                                                   const float* __restrict__ W2,
                                                   const float* __restrict__ b2,
                                                   const unsigned short* __restrict__ srcl,
                                                   const int* __restrict__ gstart,
                                                   const double* __restrict__ disd,
                                                   float* __restrict__ x3f) {
    __shared__ double h1[N_];
    __shared__ unsigned short ssrc[EG_];
    __shared__ int sstart[N_ + 1];
    __shared__ double sdis[N_];
    int g = blockIdx.x, tid = threadIdx.x;
    size_t nbase = (size_t)g * N_;

    for (int i = tid; i < EG_; i += 512) ssrc[i] = srcl[(size_t)g * EG_ + i];
    for (int i = tid; i <= N_; i += 512) sstart[i] = gstart[g * (N_ + 1) + i];
    int n = tid;
    {
        double a = 0.0;
#pragma unroll
        for (int c = 0; c < HID_; ++c)
            a = fma((double)xin[(nbase + n) * HID_ + c], (double)W2[c], a);
        h1[n] = a;
        sdis[n] = disd[nbase + n];
    }
    __syncthreads();

    int e0 = sstart[n], e1 = sstart[n + 1];
    double a = 0.0;
    for (int e = e0; e < e1; ++e) {
        int s = ssrc[e];
        a += h1[s] * sdis[s];
    }
    double dn = sdis[n];
    double v = a * dn + h1[n] * dn * dn + (double)b2[0];
    x3f[nbase + n] = (float)tanh(v);   // fp32 rank key AND feature value
}

// ---------------- per-graph head: fp32 keys, ulp-window tie -> index -------
__global__ __launch_bounds__(256) void head_kernel(const float* __restrict__ x1,
                                                   const float* __restrict__ x2,
                                                   const float* __restrict__ x3f,
                                                   const float* __restrict__ c1w,
                                                   const float* __restrict__ c1b,
                                                   const float* __restrict__ c2w,
                                                   const float* __restrict__ c2b,
                                                   const float* __restrict__ l1w,
                                                   const float* __restrict__ l1b,
                                                   const float* __restrict__ l2w,
                                                   const float* __restrict__ l2b,
                                                   float* __restrict__ out) {
    int g = blockIdx.x;
    size_t nbase = (size_t)g * N_;
    __shared__ float sv[N_];
    __shared__ int   topk[K_];
    __shared__ float pooled[K_][LAT_];
    __shared__ float c1[16][K_];
    __shared__ float mp[16][10];
    __shared__ float c2[32 * 6];
    __shared__ float l1[128];

    for (int i = threadIdx.x; i < K_; i += 256) topk[i] = i;  // fallback
    for (int i = threadIdx.x; i < N_; i += 256) sv[i] = x3f[nbase + i];
    __syncthreads();

    // top-K descending on fp32 keys; pairs within ~1.5 ulp (relative) are
    // np-fp32 ties -> stable order (lower index first).
    for (int i = threadIdx.x; i < N_; i += 256) {
        float v = sv[i];
        int rank = 0;
        for (int j = 0; j < N_; ++j) {
            float u = sv[j];
            float mag = fmaxf(fabsf(u), fabsf(v));
            bool tie = fabsf(u - v) <= EPS_REL * mag;
            bool beats = tie ? (j < i) : (u > v);
            rank += beats;
        }
        if (rank < K_) topk[rank] = i;
    }
    __syncthreads();

    for (int i = threadIdx.x; i < K_ * LAT_; i += 256) {
        int k = i / LAT_, c = i % LAT_;
        int node = topk[k];
        float f;
        if (c < HID_)            f = x1[(nbase + node) * HID_ + c];
        else if (c < 2 * HID_)   f = x2[(nbase + node) * HID_ + (c - HID_)];
        else                     f = sv[node];
        pooled[k][c] = f;
    }
    __syncthreads();

    for (int i = threadIdx.x; i < 16 * K_; i += 256) {
        int o = i / K_, k = i % K_;
        float acc = c1b[o];
        for (int c = 0; c < LAT_; ++c) acc += pooled[k][c] * c1w[o * LAT_ + c];
        c1[o][k] = fmaxf(acc, 0.f);
    }
    __syncthreads();

    for (int i = threadIdx.x; i < 160; i += 256) {
        int o = i / 10, t = i % 10;
        mp[o][t] = fmaxf(c1[o][2 * t], c1[o][2 * t + 1]);
    }
    __syncthreads();

    for (int i = threadIdx.x; i < 192; i += 256) {
        int o = i / 6, t = i % 6;
        float acc = c2b[o];
        for (int ic = 0; ic < 16; ++ic)
#pragma unroll
            for (int j = 0; j < 5; ++j)
                acc += mp[ic][t + j] * c2w[(o * 16 + ic) * 5 + j];
        c2[o * 6 + t] = fmaxf(acc, 0.f);
    }
    __syncthreads();

    for (int i = threadIdx.x; i < 128; i += 256) {
        float acc = l1b[i];
        for (int c = 0; c < 192; ++c) acc += c2[c] * l1w[c * 128 + i];
        l1[i] = fmaxf(acc, 0.f);
    }
    __syncthreads();

    for (int i = threadIdx.x; i < 2; i += 256) {
        float acc = l2b[i];
        for (int c = 0; c < 128; ++c) acc += l1[c] * l2w[c * 2 + i];
        out[g * 2 + i] = acc;
    }
}

extern "C" void kernel_launch(void* const* d_in, const int* in_sizes, int n_in,
                              void* d_out, int out_size, void* d_ws, size_t ws_size,
                              hipStream_t stream) {
    const float* x   = (const float*)d_in[0];
    const int*   ei  = (const int*)d_in[1];
    const float* W0  = (const float*)d_in[3];
    const float* b0  = (const float*)d_in[4];
    const float* W1  = (const float*)d_in[5];
    const float* b1  = (const float*)d_in[6];
    const float* W2  = (const float*)d_in[7];
    const float* b2  = (const float*)d_in[8];
    const float* c1w = (const float*)d_in[9];
    const float* c1b = (const float*)d_in[10];
    const float* c2w = (const float*)d_in[11];
    const float* c2b = (const float*)d_in[12];
    const float* l1w = (const float*)d_in[13];
    const float* l1b = (const float*)d_in[14];
    const float* l2w = (const float*)d_in[15];
    const float* l2b = (const float*)d_in[16];

    const int* src = ei;
    const int* dst = ei + (size_t)G_ * EG_;

    char* wsb = (char*)d_ws;
    double* h64  = (double*)wsb;                 wsb += (size_t)NN_ * HID_ * 8;     // 64 MiB (stripe-major)
    unsigned short* srcl = (unsigned short*)wsb; wsb += (size_t)G_ * EG_ * 2;       // 8 MiB
    int* gstart = (int*)wsb;                     wsb += (size_t)G_ * (N_ + 1) * 4;  // 1 MiB
    double* disd = (double*)wsb;                 wsb += (size_t)NN_ * 8;            // 2 MiB
    float*  x3f  = (float*)wsb;                  wsb += (size_t)NN_ * 4;            // 1 MiB
    float*  x1f  = (float*)wsb;                  wsb += (size_t)NN_ * HID_ * 4;     // 32 MiB
    float*  x2f  = (float*)wsb;                  wsb += (size_t)NN_ * HID_ * 4;     // 32 MiB

    dim3 agrid(G_, NSTRIPE);
    csr2_kernel<<<G_, 512, 0, stream>>>(src, dst, srcl, gstart, disd);
    mm_kernel<CIN_><<<NN_ / 64, 256, 0, stream>>>(x, W0, h64);
    agg_kernel<<<agrid, 512, 0, stream>>>(h64, srcl, gstart, disd, b0, x1f);
    mm_kernel<HID_><<<NN_ / 64, 256, 0, stream>>>(x1f, W1, h64);
    agg_kernel<<<agrid, 512, 0, stream>>>(h64, srcl, gstart, disd, b1, x2f);
    gcn3_kernel<<<G_, 512, 0, stream>>>(x2f, W2, b2, srcl, gstart, disd, x3f);
    head_kernel<<<G_, 256, 0, stream>>>(x1f, x2f, x3f, c1w, c1b, c2w, c2b,
                                        l1w, l1b, l2w, l2b, (float*)d_out);
}

// Round 14
// 429.904 us; speedup vs baseline: 1.3619x; 1.0298x over previous
//
#include <hip/hip_runtime.h>
#include <math.h>

#define G_ 512
#define N_ 512
#define NN_ (G_*N_)
#define EG_ 8192
#define CIN_ 128
#define HID_ 32
#define K_ 20
#define LAT_ 65
#define NSTRIPE 4
#define SW 8          // channels per stripe

// relative tie window: ~1.5 ulp of fp32 (2^-23 = 1.19e-7)
#define EPS_REL 1.8e-7f

// ---------------- CSR build v2: atomic count/place + per-bin sort ----------
__global__ __launch_bounds__(512) void csr2_kernel(const int* __restrict__ src,
                                                   const int* __restrict__ dst,
                                                   unsigned short* __restrict__ srcl,
                                                   int* __restrict__ gstart,
                                                   double* __restrict__ disd) {
    __shared__ int cnt[N_];
    __shared__ int startv[N_];
    __shared__ int tmpv[N_];
    __shared__ int cursor[N_];
    __shared__ unsigned short binE[EG_];
    int g = blockIdx.x, tid = threadIdx.x;
    const int* ds = dst + (size_t)g * EG_;
    const int* ss = src + (size_t)g * EG_;
    int nb = g * N_;

    cnt[tid] = 0;
    __syncthreads();
    for (int e = tid; e < EG_; e += 512) atomicAdd(&cnt[ds[e] - nb], 1);
    __syncthreads();

    startv[tid] = cnt[tid];
    __syncthreads();
    for (int off = 1; off < N_; off <<= 1) {
        tmpv[tid] = startv[tid] + (tid >= off ? startv[tid - off] : 0);
        __syncthreads();
        startv[tid] = tmpv[tid];
        __syncthreads();
    }

    int excl = startv[tid] - cnt[tid];
    cursor[tid] = excl;
    gstart[g * (N_ + 1) + tid] = excl;
    if (tid == 0) gstart[g * (N_ + 1) + N_] = EG_;
    disd[nb + tid] = 1.0 / sqrt((double)(cnt[tid] + 1));
    __syncthreads();

    for (int e = tid; e < EG_; e += 512) {
        int d = ds[e] - nb;
        int slot = atomicAdd(&cursor[d], 1);
        binE[slot] = (unsigned short)e;
    }
    __syncthreads();

    {
        int n = cnt[tid];
        for (int i = 1; i < n; ++i) {
            unsigned short key = binE[excl + i];
            int j = i - 1;
            while (j >= 0 && binE[excl + j] > key) {
                binE[excl + j + 1] = binE[excl + j];
                --j;
            }
            binE[excl + j + 1] = key;
        }
    }
    __syncthreads();

    for (int i = tid; i < EG_; i += 512) {
        int e = binE[i];
        srcl[(size_t)g * EG_ + i] = (unsigned short)(ss[e] - nb);
    }
}

// ---------------- matmul: h[n][o] = sum_c x[n][c]*W[c][o], fp64 acc --------
// 128 nodes/block, 256 threads: thread = (q = tid>>4 -> 8 nodes, o2 = tid&15
// -> channels o2 and o2+16). Per-acc fma chain is c-ascending — bit-identical
// to previous rounds. W kept fp32 in LDS (cvt at use) to fit 80 KB/block.
// Writes h stripe-major: h[((o/8)*NN + n)*8 + o%8].
template <int CI>
__global__ __launch_bounds__(256) void mm_kernel(const float* __restrict__ xin,
                                                 const float* __restrict__ W,
                                                 double* __restrict__ h) {
    __shared__ float sx[128][CI];        // CI=128: 64 KB ; CI=32: 16 KB
    __shared__ float sW[CI][HID_];       // CI=128: 16 KB ; CI=32: 4 KB
    int tid = threadIdx.x;
    for (int i = tid; i < CI * HID_; i += 256) sW[i / HID_][i % HID_] = W[i];
    size_t base = (size_t)blockIdx.x * 128;
    const float4* xsrc = (const float4*)(xin + base * CI);
    float4* dst4 = (float4*)&sx[0][0];
    for (int i = tid; i < 128 * CI / 4; i += 256) dst4[i] = xsrc[i];
    __syncthreads();

    int o2 = tid & 15, q = tid >> 4;     // 16 q-groups x 8 nodes
    int n0 = q * 8;
    double acc[8][2];
#pragma unroll
    for (int j = 0; j < 8; ++j) { acc[j][0] = 0.0; acc[j][1] = 0.0; }

    for (int c = 0; c < CI; c += 4) {
        double w0a = (double)sW[c][o2],     w0b = (double)sW[c][o2 + 16];
        double w1a = (double)sW[c + 1][o2], w1b = (double)sW[c + 1][o2 + 16];
        double w2a = (double)sW[c + 2][o2], w2b = (double)sW[c + 2][o2 + 16];
        double w3a = (double)sW[c + 3][o2], w3b = (double)sW[c + 3][o2 + 16];
#pragma unroll
        for (int j = 0; j < 8; ++j) {
            float4 v = *(const float4*)&sx[n0 + j][c];
            double vx = (double)v.x, vy = (double)v.y,
                   vz = (double)v.z, vw = (double)v.w;
            acc[j][0] = fma(vx, w0a, acc[j][0]);
            acc[j][0] = fma(vy, w1a, acc[j][0]);
            acc[j][0] = fma(vz, w2a, acc[j][0]);
            acc[j][0] = fma(vw, w3a, acc[j][0]);
            acc[j][1] = fma(vx, w0b, acc[j][1]);
            acc[j][1] = fma(vy, w1b, acc[j][1]);
            acc[j][1] = fma(vz, w2b, acc[j][1]);
            acc[j][1] = fma(vw, w3b, acc[j][1]);
        }
    }
#pragma unroll
    for (int j = 0; j < 8; ++j) {
#pragma unroll
        for (int p = 0; p < 2; ++p) {
            int o = o2 + 16 * p;
            h[(((size_t)(o >> 3)) * NN_ + base + n0 + j) * SW + (o & 7)] = acc[j][p];
        }
    }
}

// ---------------- aggregation: stripe-split, hd2 pre-scaled in LDS ---------
__global__ __launch_bounds__(512) void agg_kernel(const double* __restrict__ h,
                                                  const unsigned short* __restrict__ srcl,
                                                  const int* __restrict__ gstart,
                                                  const double* __restrict__ disd,
                                                  const float* __restrict__ bias,
                                                  float* __restrict__ xoutf) {
    __shared__ double hd2[N_ * 9];          // padded [512][9] = 36.9 KB
    __shared__ unsigned short ssrc[EG_];    // 16 KB
    __shared__ int sstart[N_ + 1];
    __shared__ double sdis[N_];             // 4 KB
    int g = blockIdx.x, st = blockIdx.y, tid = threadIdx.x;
    size_t nbase = (size_t)g * N_;

    for (int i = tid; i < EG_; i += 512) ssrc[i] = srcl[(size_t)g * EG_ + i];
    for (int i = tid; i <= N_; i += 512) sstart[i] = gstart[g * (N_ + 1) + i];
    sdis[tid] = disd[nbase + tid];
    __syncthreads();

    const double* hraw = h + ((size_t)st * NN_ + nbase) * SW;
    for (int i = tid; i < N_ * SW; i += 512)
        hd2[(i >> 3) * 9 + (i & 7)] = hraw[i] * sdis[i >> 3];
    __syncthreads();

    int oc = tid & 7, grp = tid >> 3;   // 64 node-groups x 8 channels
    double b = (double)bias[st * SW + oc];

    int e0[8], e1[8];
    double a[8];
    int mx = 0;
#pragma unroll
    for (int j = 0; j < 8; ++j) {
        int n = grp + j * 64;
        e0[j] = sstart[n];
        e1[j] = sstart[n + 1];
        a[j] = 0.0;
        int d = e1[j] - e0[j];
        mx = d > mx ? d : mx;
    }
    for (int t = 0; t < mx; ++t) {
#pragma unroll
        for (int j = 0; j < 8; ++j) {
            int idx = e0[j] + t;
            if (idx < e1[j]) {
                int s = ssrc[idx];
                a[j] += hd2[s * 9 + oc];
            }
        }
    }
#pragma unroll
    for (int j = 0; j < 8; ++j) {
        int n = grp + j * 64;
        double dn = sdis[n];
        double v = a[j] * dn + hd2[n * 9 + oc] * dn + b;
        xoutf[(nbase + n) * HID_ + st * SW + oc] = tanhf((float)v);
    }
}

// ---------------- layer 3 (32 -> 1): fp32 key = round(fp64 tanh) -----------
__global__ __launch_bounds__(512) void gcn3_kernel(const float* __restrict__ xin,
                                                   const float* __restrict__ W2,
                                                   const float* __restrict__ b2,
                                                   const unsigned short* __restrict__ srcl,
                                                   const int* __restrict__ gstart,
                                                   const double* __restrict__ disd,
                                                   float* __restrict__ x3f) {
    __shared__ double h1[N_];
    __shared__ unsigned short ssrc[EG_];
    __shared__ int sstart[N_ + 1];
    __shared__ double sdis[N_];
    int g = blockIdx.x, tid = threadIdx.x;
    size_t nbase = (size_t)g * N_;

    for (int i = tid; i < EG_; i += 512) ssrc[i] = srcl[(size_t)g * EG_ + i];
    for (int i = tid; i <= N_; i += 512) sstart[i] = gstart[g * (N_ + 1) + i];
    int n = tid;
    {
        double a = 0.0;
#pragma unroll
        for (int c = 0; c < HID_; ++c)
            a = fma((double)xin[(nbase + n) * HID_ + c], (double)W2[c], a);
        h1[n] = a;
        sdis[n] = disd[nbase + n];
    }
    __syncthreads();

    int e0 = sstart[n], e1 = sstart[n + 1];
    double a = 0.0;
    for (int e = e0; e < e1; ++e) {
        int s = ssrc[e];
        a += h1[s] * sdis[s];
    }
    double dn = sdis[n];
    double v = a * dn + h1[n] * dn * dn + (double)b2[0];
    x3f[nbase + n] = (float)tanh(v);   // fp32 rank key AND feature value
}

// ---------------- per-graph head: fp32 keys, ulp-window tie -> index -------
__global__ __launch_bounds__(256) void head_kernel(const float* __restrict__ x1,
                                                   const float* __restrict__ x2,
                                                   const float* __restrict__ x3f,
                                                   const float* __restrict__ c1w,
                                                   const float* __restrict__ c1b,
                                                   const float* __restrict__ c2w,
                                                   const float* __restrict__ c2b,
                                                   const float* __restrict__ l1w,
                                                   const float* __restrict__ l1b,
                                                   const float* __restrict__ l2w,
                                                   const float* __restrict__ l2b,
                                                   float* __restrict__ out) {
    int g = blockIdx.x;
    size_t nbase = (size_t)g * N_;
    __shared__ float sv[N_];
    __shared__ int   topk[K_];
    __shared__ float pooled[K_][LAT_];
    __shared__ float c1[16][K_];
    __shared__ float mp[16][10];
    __shared__ float c2[32 * 6];
    __shared__ float l1[128];

    for (int i = threadIdx.x; i < K_; i += 256) topk[i] = i;  // fallback
    for (int i = threadIdx.x; i < N_; i += 256) sv[i] = x3f[nbase + i];
    __syncthreads();

    // top-K descending on fp32 keys; pairs within ~1.5 ulp (relative) are
    // np-fp32 ties -> stable order (lower index first).
    for (int i = threadIdx.x; i < N_; i += 256) {
        float v = sv[i];
        int rank = 0;
        for (int j = 0; j < N_; ++j) {
            float u = sv[j];
            float mag = fmaxf(fabsf(u), fabsf(v));
            bool tie = fabsf(u - v) <= EPS_REL * mag;
            bool beats = tie ? (j < i) : (u > v);
            rank += beats;
        }
        if (rank < K_) topk[rank] = i;
    }
    __syncthreads();

    for (int i = threadIdx.x; i < K_ * LAT_; i += 256) {
        int k = i / LAT_, c = i % LAT_;
        int node = topk[k];
        float f;
        if (c < HID_)            f = x1[(nbase + node) * HID_ + c];
        else if (c < 2 * HID_)   f = x2[(nbase + node) * HID_ + (c - HID_)];
        else                     f = sv[node];
        pooled[k][c] = f;
    }
    __syncthreads();

    for (int i = threadIdx.x; i < 16 * K_; i += 256) {
        int o = i / K_, k = i % K_;
        float acc = c1b[o];
        for (int c = 0; c < LAT_; ++c) acc += pooled[k][c] * c1w[o * LAT_ + c];
        c1[o][k] = fmaxf(acc, 0.f);
    }
    __syncthreads();

    for (int i = threadIdx.x; i < 160; i += 256) {
        int o = i / 10, t = i % 10;
        mp[o][t] = fmaxf(c1[o][2 * t], c1[o][2 * t + 1]);
    }
    __syncthreads();

    for (int i = threadIdx.x; i < 192; i += 256) {
        int o = i / 6, t = i % 6;
        float acc = c2b[o];
        for (int ic = 0; ic < 16; ++ic)
#pragma unroll
            for (int j = 0; j < 5; ++j)
                acc += mp[ic][t + j] * c2w[(o * 16 + ic) * 5 + j];
        c2[o * 6 + t] = fmaxf(acc, 0.f);
    }
    __syncthreads();

    for (int i = threadIdx.x; i < 128; i += 256) {
        float acc = l1b[i];
        for (int c = 0; c < 192; ++c) acc += c2[c] * l1w[c * 128 + i];
        l1[i] = fmaxf(acc, 0.f);
    }
    __syncthreads();

    for (int i = threadIdx.x; i < 2; i += 256) {
        float acc = l2b[i];
        for (int c = 0; c < 128; ++c) acc += l1[c] * l2w[c * 2 + i];
        out[g * 2 + i] = acc;
    }
}

extern "C" void kernel_launch(void* const* d_in, const int* in_sizes, int n_in,
                              void* d_out, int out_size, void* d_ws, size_t ws_size,
                              hipStream_t stream) {
    const float* x   = (const float*)d_in[0];
    const int*   ei  = (const int*)d_in[1];
    const float* W0  = (const float*)d_in[3];
    const float* b0  = (const float*)d_in[4];
    const float* W1  = (const float*)d_in[5];
    const float* b1  = (const float*)d_in[6];
    const float* W2  = (const float*)d_in[7];
    const float* b2  = (const float*)d_in[8];
    const float* c1w = (const float*)d_in[9];
    const float* c1b = (const float*)d_in[10];
    const float* c2w = (const float*)d_in[11];
    const float* c2b = (const float*)d_in[12];
    const float* l1w = (const float*)d_in[13];
    const float* l1b = (const float*)d_in[14];
    const float* l2w = (const float*)d_in[15];
    const float* l2b = (const float*)d_in[16];

    const int* src = ei;
    const int* dst = ei + (size_t)G_ * EG_;

    char* wsb = (char*)d_ws;
    double* h64  = (double*)wsb;                 wsb += (size_t)NN_ * HID_ * 8;     // 64 MiB (stripe-major)
    unsigned short* srcl = (unsigned short*)wsb; wsb += (size_t)G_ * EG_ * 2;       // 8 MiB
    int* gstart = (int*)wsb;                     wsb += (size_t)G_ * (N_ + 1) * 4;  // 1 MiB
    double* disd = (double*)wsb;                 wsb += (size_t)NN_ * 8;            // 2 MiB
    float*  x3f  = (float*)wsb;                  wsb += (size_t)NN_ * 4;            // 1 MiB
    float*  x1f  = (float*)wsb;                  wsb += (size_t)NN_ * HID_ * 4;     // 32 MiB
    float*  x2f  = (float*)wsb;                  wsb += (size_t)NN_ * HID_ * 4;     // 32 MiB

    dim3 agrid(G_, NSTRIPE);
    csr2_kernel<<<G_, 512, 0, stream>>>(src, dst, srcl, gstart, disd);
    mm_kernel<CIN_><<<NN_ / 128, 256, 0, stream>>>(x, W0, h64);
    agg_kernel<<<agrid, 512, 0, stream>>>(h64, srcl, gstart, disd, b0, x1f);
    mm_kernel<HID_><<<NN_ / 128, 256, 0, stream>>>(x1f, W1, h64);
    agg_kernel<<<agrid, 512, 0, stream>>>(h64, srcl, gstart, disd, b1, x2f);
    gcn3_kernel<<<G_, 512, 0, stream>>>(x2f, W2, b2, srcl, gstart, disd, x3f);
    head_kernel<<<G_, 256, 0, stream>>>(x1f, x2f, x3f, c1w, c1b, c2w, c2b,
                                        l1w, l1b, l2w, l2b, (float*)d_out);
}

// Round 15
// 412.024 us; speedup vs baseline: 1.4210x; 1.0434x over previous
//
#include <hip/hip_runtime.h>
#include <math.h>

#define G_ 512
#define N_ 512
#define NN_ (G_*N_)
#define EG_ 8192
#define CIN_ 128
#define HID_ 32
#define K_ 20
#define LAT_ 65
#define NSTRIPE 4
#define SW 8          // channels per stripe

// relative tie window: ~1.5 ulp of fp32 (2^-23 = 1.19e-7)
#define EPS_REL 1.8e-7f

// ---------------- CSR build v2: atomic count/place + per-bin sort ----------
__global__ __launch_bounds__(512) void csr2_kernel(const int* __restrict__ src,
                                                   const int* __restrict__ dst,
                                                   unsigned short* __restrict__ srcl,
                                                   int* __restrict__ gstart,
                                                   double* __restrict__ disd) {
    __shared__ int cnt[N_];
    __shared__ int startv[N_];
    __shared__ int tmpv[N_];
    __shared__ int cursor[N_];
    __shared__ unsigned short binE[EG_];
    int g = blockIdx.x, tid = threadIdx.x;
    const int* ds = dst + (size_t)g * EG_;
    const int* ss = src + (size_t)g * EG_;
    int nb = g * N_;

    cnt[tid] = 0;
    __syncthreads();
    for (int e = tid; e < EG_; e += 512) atomicAdd(&cnt[ds[e] - nb], 1);
    __syncthreads();

    startv[tid] = cnt[tid];
    __syncthreads();
    for (int off = 1; off < N_; off <<= 1) {
        tmpv[tid] = startv[tid] + (tid >= off ? startv[tid - off] : 0);
        __syncthreads();
        startv[tid] = tmpv[tid];
        __syncthreads();
    }

    int excl = startv[tid] - cnt[tid];
    cursor[tid] = excl;
    gstart[g * (N_ + 1) + tid] = excl;
    if (tid == 0) gstart[g * (N_ + 1) + N_] = EG_;
    disd[nb + tid] = 1.0 / sqrt((double)(cnt[tid] + 1));
    __syncthreads();

    for (int e = tid; e < EG_; e += 512) {
        int d = ds[e] - nb;
        int slot = atomicAdd(&cursor[d], 1);
        binE[slot] = (unsigned short)e;
    }
    __syncthreads();

    {
        int n = cnt[tid];
        for (int i = 1; i < n; ++i) {
            unsigned short key = binE[excl + i];
            int j = i - 1;
            while (j >= 0 && binE[excl + j] > key) {
                binE[excl + j + 1] = binE[excl + j];
                --j;
            }
            binE[excl + j + 1] = key;
        }
    }
    __syncthreads();

    for (int i = tid; i < EG_; i += 512) {
        int e = binE[i];
        srcl[(size_t)g * EG_ + i] = (unsigned short)(ss[e] - nb);
    }
}

// ---------------- matmul: h[n][o] = sum_c x[n][c]*W[c][o], fp64 acc --------
// 64 nodes/block, 256 threads: thread = (q = tid>>4 -> 4 nodes, o2 = tid&15
// -> channels o2 and o2+16). 8 indep fp64 chains/thread; c-ascending fma
// per chain (bit-identical). sx rows padded +4 floats: wave's q-groups land
// 2-way-aliased on banks (free) instead of 4-way. LDS ~50 KB -> 3 blocks/CU.
// Writes h stripe-major: h[((o/8)*NN + n)*8 + o%8].
template <int CI>
__global__ __launch_bounds__(256) void mm_kernel(const float* __restrict__ xin,
                                                 const float* __restrict__ W,
                                                 double* __restrict__ h) {
    __shared__ float sx[64][CI + 4];     // CI=128: 33.8 KB ; CI=32: 9.2 KB
    __shared__ float sW[CI][HID_];       // CI=128: 16 KB ; CI=32: 4 KB
    int tid = threadIdx.x;
    for (int i = tid; i < CI * HID_; i += 256) sW[i / HID_][i % HID_] = W[i];
    size_t base = (size_t)blockIdx.x * 64;
    const float4* xsrc = (const float4*)(xin + base * CI);
    for (int i = tid; i < 64 * CI / 4; i += 256) {
        int row = i / (CI / 4), col = (i % (CI / 4)) * 4;
        *(float4*)&sx[row][col] = xsrc[i];
    }
    __syncthreads();

    int o2 = tid & 15, q = tid >> 4;     // 16 q-groups x 4 nodes
    int n0 = q * 4;
    double acc[4][2];
#pragma unroll
    for (int j = 0; j < 4; ++j) { acc[j][0] = 0.0; acc[j][1] = 0.0; }

    for (int c = 0; c < CI; c += 4) {
        double w0a = (double)sW[c][o2],     w0b = (double)sW[c][o2 + 16];
        double w1a = (double)sW[c + 1][o2], w1b = (double)sW[c + 1][o2 + 16];
        double w2a = (double)sW[c + 2][o2], w2b = (double)sW[c + 2][o2 + 16];
        double w3a = (double)sW[c + 3][o2], w3b = (double)sW[c + 3][o2 + 16];
#pragma unroll
        for (int j = 0; j < 4; ++j) {
            float4 v = *(const float4*)&sx[n0 + j][c];
            double vx = (double)v.x, vy = (double)v.y,
                   vz = (double)v.z, vw = (double)v.w;
            acc[j][0] = fma(vx, w0a, acc[j][0]);
            acc[j][0] = fma(vy, w1a, acc[j][0]);
            acc[j][0] = fma(vz, w2a, acc[j][0]);
            acc[j][0] = fma(vw, w3a, acc[j][0]);
            acc[j][1] = fma(vx, w0b, acc[j][1]);
            acc[j][1] = fma(vy, w1b, acc[j][1]);
            acc[j][1] = fma(vz, w2b, acc[j][1]);
            acc[j][1] = fma(vw, w3b, acc[j][1]);
        }
    }
#pragma unroll
    for (int j = 0; j < 4; ++j) {
#pragma unroll
        for (int p = 0; p < 2; ++p) {
            int o = o2 + 16 * p;
            h[(((size_t)(o >> 3)) * NN_ + base + n0 + j) * SW + (o & 7)] = acc[j][p];
        }
    }
}

// ---------------- aggregation: stripe-split, hd2 pre-scaled in LDS ---------
__global__ __launch_bounds__(512) void agg_kernel(const double* __restrict__ h,
                                                  const unsigned short* __restrict__ srcl,
                                                  const int* __restrict__ gstart,
                                                  const double* __restrict__ disd,
                                                  const float* __restrict__ bias,
                                                  float* __restrict__ xoutf) {
    __shared__ double hd2[N_ * 9];          // padded [512][9] = 36.9 KB
    __shared__ unsigned short ssrc[EG_];    // 16 KB
    __shared__ int sstart[N_ + 1];
    __shared__ double sdis[N_];             // 4 KB
    int g = blockIdx.x, st = blockIdx.y, tid = threadIdx.x;
    size_t nbase = (size_t)g * N_;

    for (int i = tid; i < EG_; i += 512) ssrc[i] = srcl[(size_t)g * EG_ + i];
    for (int i = tid; i <= N_; i += 512) sstart[i] = gstart[g * (N_ + 1) + i];
    sdis[tid] = disd[nbase + tid];
    __syncthreads();

    const double* hraw = h + ((size_t)st * NN_ + nbase) * SW;
    for (int i = tid; i < N_ * SW; i += 512)
        hd2[(i >> 3) * 9 + (i & 7)] = hraw[i] * sdis[i >> 3];
    __syncthreads();

    int oc = tid & 7, grp = tid >> 3;   // 64 node-groups x 8 channels
    double b = (double)bias[st * SW + oc];

    int e0[8], e1[8];
    double a[8];
    int mx = 0;
#pragma unroll
    for (int j = 0; j < 8; ++j) {
        int n = grp + j * 64;
        e0[j] = sstart[n];
        e1[j] = sstart[n + 1];
        a[j] = 0.0;
        int d = e1[j] - e0[j];
        mx = d > mx ? d : mx;
    }
    for (int t = 0; t < mx; ++t) {
#pragma unroll
        for (int j = 0; j < 8; ++j) {
            int idx = e0[j] + t;
            if (idx < e1[j]) {
                int s = ssrc[idx];
                a[j] += hd2[s * 9 + oc];
            }
        }
    }
#pragma unroll
    for (int j = 0; j < 8; ++j) {
        int n = grp + j * 64;
        double dn = sdis[n];
        double v = a[j] * dn + hd2[n * 9 + oc] * dn + b;
        xoutf[(nbase + n) * HID_ + st * SW + oc] = tanhf((float)v);
    }
}

// ---------------- layer 3 (32 -> 1): fp32 key = round(fp64 tanh) -----------
__global__ __launch_bounds__(512) void gcn3_kernel(const float* __restrict__ xin,
                                                   const float* __restrict__ W2,
                                                   const float* __restrict__ b2,
                                                   const unsigned short* __restrict__ srcl,
                                                   const int* __restrict__ gstart,
                                                   const double* __restrict__ disd,
                                                   float* __restrict__ x3f) {
    __shared__ double h1[N_];
    __shared__ unsigned short ssrc[EG_];
    __shared__ int sstart[N_ + 1];
    __shared__ double sdis[N_];
    int g = blockIdx.x, tid = threadIdx.x;
    size_t nbase = (size_t)g * N_;

    for (int i = tid; i < EG_; i += 512) ssrc[i] = srcl[(size_t)g * EG_ + i];
    for (int i = tid; i <= N_; i += 512) sstart[i] = gstart[g * (N_ + 1) + i];
    int n = tid;
    {
        double a = 0.0;
#pragma unroll
        for (int c = 0; c < HID_; ++c)
            a = fma((double)xin[(nbase + n) * HID_ + c], (double)W2[c], a);
        h1[n] = a;
        sdis[n] = disd[nbase + n];
    }
    __syncthreads();

    int e0 = sstart[n], e1 = sstart[n + 1];
    double a = 0.0;
    for (int e = e0; e < e1; ++e) {
        int s = ssrc[e];
        a += h1[s] * sdis[s];
    }
    double dn = sdis[n];
    double v = a * dn + h1[n] * dn * dn + (double)b2[0];
    x3f[nbase + n] = (float)tanh(v);   // fp32 rank key AND feature value
}

// ---------------- per-graph head: fp32 keys, ulp-window tie -> index -------
__global__ __launch_bounds__(256) void head_kernel(const float* __restrict__ x1,
                                                   const float* __restrict__ x2,
                                                   const float* __restrict__ x3f,
                                                   const float* __restrict__ c1w,
                                                   const float* __restrict__ c1b,
                                                   const float* __restrict__ c2w,
                                                   const float* __restrict__ c2b,
                                                   const float* __restrict__ l1w,
                                                   const float* __restrict__ l1b,
                                                   const float* __restrict__ l2w,
                                                   const float* __restrict__ l2b,
                                                   float* __restrict__ out) {
    int g = blockIdx.x;
    size_t nbase = (size_t)g * N_;
    __shared__ float sv[N_];
    __shared__ int   topk[K_];
    __shared__ float pooled[K_][LAT_];
    __shared__ float c1[16][K_];
    __shared__ float mp[16][10];
    __shared__ float c2[32 * 6];
    __shared__ float l1[128];

    for (int i = threadIdx.x; i < K_; i += 256) topk[i] = i;  // fallback
    for (int i = threadIdx.x; i < N_; i += 256) sv[i] = x3f[nbase + i];
    __syncthreads();

    // top-K descending on fp32 keys; pairs within ~1.5 ulp (relative) are
    // np-fp32 ties -> stable order (lower index first).
    for (int i = threadIdx.x; i < N_; i += 256) {
        float v = sv[i];
        int rank = 0;
        for (int j = 0; j < N_; ++j) {
            float u = sv[j];
            float mag = fmaxf(fabsf(u), fabsf(v));
            bool tie = fabsf(u - v) <= EPS_REL * mag;
            bool beats = tie ? (j < i) : (u > v);
            rank += beats;
        }
        if (rank < K_) topk[rank] = i;
    }
    __syncthreads();

    for (int i = threadIdx.x; i < K_ * LAT_; i += 256) {
        int k = i / LAT_, c = i % LAT_;
        int node = topk[k];
        float f;
        if (c < HID_)            f = x1[(nbase + node) * HID_ + c];
        else if (c < 2 * HID_)   f = x2[(nbase + node) * HID_ + (c - HID_)];
        else                     f = sv[node];
        pooled[k][c] = f;
    }
    __syncthreads();

    for (int i = threadIdx.x; i < 16 * K_; i += 256) {
        int o = i / K_, k = i % K_;
        float acc = c1b[o];
        for (int c = 0; c < LAT_; ++c) acc += pooled[k][c] * c1w[o * LAT_ + c];
        c1[o][k] = fmaxf(acc, 0.f);
    }
    __syncthreads();

    for (int i = threadIdx.x; i < 160; i += 256) {
        int o = i / 10, t = i % 10;
        mp[o][t] = fmaxf(c1[o][2 * t], c1[o][2 * t + 1]);
    }
    __syncthreads();

    for (int i = threadIdx.x; i < 192; i += 256) {
        int o = i / 6, t = i % 6;
        float acc = c2b[o];
        for (int ic = 0; ic < 16; ++ic)
#pragma unroll
            for (int j = 0; j < 5; ++j)
                acc += mp[ic][t + j] * c2w[(o * 16 + ic) * 5 + j];
        c2[o * 6 + t] = fmaxf(acc, 0.f);
    }
    __syncthreads();

    for (int i = threadIdx.x; i < 128; i += 256) {
        float acc = l1b[i];
        for (int c = 0; c < 192; ++c) acc += c2[c] * l1w[c * 128 + i];
        l1[i] = fmaxf(acc, 0.f);
    }
    __syncthreads();

    for (int i = threadIdx.x; i < 2; i += 256) {
        float acc = l2b[i];
        for (int c = 0; c < 128; ++c) acc += l1[c] * l2w[c * 2 + i];
        out[g * 2 + i] = acc;
    }
}

extern "C" void kernel_launch(void* const* d_in, const int* in_sizes, int n_in,
                              void* d_out, int out_size, void* d_ws, size_t ws_size,
                              hipStream_t stream) {
    const float* x   = (const float*)d_in[0];
    const int*   ei  = (const int*)d_in[1];
    const float* W0  = (const float*)d_in[3];
    const float* b0  = (const float*)d_in[4];
    const float* W1  = (const float*)d_in[5];
    const float* b1  = (const float*)d_in[6];
    const float* W2  = (const float*)d_in[7];
    const float* b2  = (const float*)d_in[8];
    const float* c1w = (const float*)d_in[9];
    const float* c1b = (const float*)d_in[10];
    const float* c2w = (const float*)d_in[11];
    const float* c2b = (const float*)d_in[12];
    const float* l1w = (const float*)d_in[13];
    const float* l1b = (const float*)d_in[14];
    const float* l2w = (const float*)d_in[15];
    const float* l2b = (const float*)d_in[16];

    const int* src = ei;
    const int* dst = ei + (size_t)G_ * EG_;

    char* wsb = (char*)d_ws;
    double* h64  = (double*)wsb;                 wsb += (size_t)NN_ * HID_ * 8;     // 64 MiB (stripe-major)
    unsigned short* srcl = (unsigned short*)wsb; wsb += (size_t)G_ * EG_ * 2;       // 8 MiB
    int* gstart = (int*)wsb;                     wsb += (size_t)G_ * (N_ + 1) * 4;  // 1 MiB
    double* disd = (double*)wsb;                 wsb += (size_t)NN_ * 8;            // 2 MiB
    float*  x3f  = (float*)wsb;                  wsb += (size_t)NN_ * 4;            // 1 MiB
    float*  x1f  = (float*)wsb;                  wsb += (size_t)NN_ * HID_ * 4;     // 32 MiB
    float*  x2f  = (float*)wsb;                  wsb += (size_t)NN_ * HID_ * 4;     // 32 MiB

    dim3 agrid(G_, NSTRIPE);
    csr2_kernel<<<G_, 512, 0, stream>>>(src, dst, srcl, gstart, disd);
    mm_kernel<CIN_><<<NN_ / 64, 256, 0, stream>>>(x, W0, h64);
    agg_kernel<<<agrid, 512, 0, stream>>>(h64, srcl, gstart, disd, b0, x1f);
    mm_kernel<HID_><<<NN_ / 64, 256, 0, stream>>>(x1f, W1, h64);
    agg_kernel<<<agrid, 512, 0, stream>>>(h64, srcl, gstart, disd, b1, x2f);
    gcn3_kernel<<<G_, 512, 0, stream>>>(x2f, W2, b2, srcl, gstart, disd, x3f);
    head_kernel<<<G_, 256, 0, stream>>>(x1f, x2f, x3f, c1w, c1b, c2w, c2b,
                                        l1w, l1b, l2w, l2b, (float*)d_out);
}

// Round 16
// 390.319 us; speedup vs baseline: 1.5001x; 1.0556x over previous
//
#include <hip/hip_runtime.h>
#include <math.h>

#define G_ 512
#define N_ 512
#define NN_ (G_*N_)
#define EG_ 8192
#define CIN_ 128
#define HID_ 32
#define K_ 20
#define LAT_ 65
#define NSTRIPE 4
#define SW 8          // channels per stripe
#define HP 514        // hd2 row pitch (doubles): 4-bank channel stride

// relative tie window: ~1.5 ulp of fp32 (2^-23 = 1.19e-7)
#define EPS_REL 1.8e-7f

// ---------------- CSR build v2: atomic count/place + per-bin sort ----------
__global__ __launch_bounds__(512) void csr2_kernel(const int* __restrict__ src,
                                                   const int* __restrict__ dst,
                                                   unsigned short* __restrict__ srcl,
                                                   int* __restrict__ gstart,
                                                   double* __restrict__ disd) {
    __shared__ int cnt[N_];
    __shared__ int startv[N_];
    __shared__ int tmpv[N_];
    __shared__ int cursor[N_];
    __shared__ unsigned short binE[EG_];
    int g = blockIdx.x, tid = threadIdx.x;
    const int* ds = dst + (size_t)g * EG_;
    const int* ss = src + (size_t)g * EG_;
    int nb = g * N_;

    cnt[tid] = 0;
    __syncthreads();
    for (int e = tid; e < EG_; e += 512) atomicAdd(&cnt[ds[e] - nb], 1);
    __syncthreads();

    startv[tid] = cnt[tid];
    __syncthreads();
    for (int off = 1; off < N_; off <<= 1) {
        tmpv[tid] = startv[tid] + (tid >= off ? startv[tid - off] : 0);
        __syncthreads();
        startv[tid] = tmpv[tid];
        __syncthreads();
    }

    int excl = startv[tid] - cnt[tid];
    cursor[tid] = excl;
    gstart[g * (N_ + 1) + tid] = excl;
    if (tid == 0) gstart[g * (N_ + 1) + N_] = EG_;
    disd[nb + tid] = 1.0 / sqrt((double)(cnt[tid] + 1));
    __syncthreads();

    for (int e = tid; e < EG_; e += 512) {
        int d = ds[e] - nb;
        int slot = atomicAdd(&cursor[d], 1);
        binE[slot] = (unsigned short)e;
    }
    __syncthreads();

    {
        int n = cnt[tid];
        for (int i = 1; i < n; ++i) {
            unsigned short key = binE[excl + i];
            int j = i - 1;
            while (j >= 0 && binE[excl + j] > key) {
                binE[excl + j + 1] = binE[excl + j];
                --j;
            }
            binE[excl + j + 1] = key;
        }
    }
    __syncthreads();

    for (int i = tid; i < EG_; i += 512) {
        int e = binE[i];
        srcl[(size_t)g * EG_ + i] = (unsigned short)(ss[e] - nb);
    }
}

// ---------------- matmul: h[n][o] = sum_c x[n][c]*W[c][o], fp64 acc --------
// 64 nodes/block, 256 threads: thread = (q = tid>>4 -> 4 nodes, o2 = tid&15
// -> channels o2 and o2+16). 8 indep fp64 chains/thread; c-ascending fma
// per chain (bit-identical). LDS ~50 KB -> 3 blocks/CU.
// Writes h stripe-major: h[((o/8)*NN + n)*8 + o%8].
template <int CI>
__global__ __launch_bounds__(256) void mm_kernel(const float* __restrict__ xin,
                                                 const float* __restrict__ W,
                                                 double* __restrict__ h) {
    __shared__ float sx[64][CI + 4];     // CI=128: 33.8 KB ; CI=32: 9.2 KB
    __shared__ float sW[CI][HID_];       // CI=128: 16 KB ; CI=32: 4 KB
    int tid = threadIdx.x;
    for (int i = tid; i < CI * HID_; i += 256) sW[i / HID_][i % HID_] = W[i];
    size_t base = (size_t)blockIdx.x * 64;
    const float4* xsrc = (const float4*)(xin + base * CI);
    for (int i = tid; i < 64 * CI / 4; i += 256) {
        int row = i / (CI / 4), col = (i % (CI / 4)) * 4;
        *(float4*)&sx[row][col] = xsrc[i];
    }
    __syncthreads();

    int o2 = tid & 15, q = tid >> 4;     // 16 q-groups x 4 nodes
    int n0 = q * 4;
    double acc[4][2];
#pragma unroll
    for (int j = 0; j < 4; ++j) { acc[j][0] = 0.0; acc[j][1] = 0.0; }

    for (int c = 0; c < CI; c += 4) {
        double w0a = (double)sW[c][o2],     w0b = (double)sW[c][o2 + 16];
        double w1a = (double)sW[c + 1][o2], w1b = (double)sW[c + 1][o2 + 16];
        double w2a = (double)sW[c + 2][o2], w2b = (double)sW[c + 2][o2 + 16];
        double w3a = (double)sW[c + 3][o2], w3b = (double)sW[c + 3][o2 + 16];
#pragma unroll
        for (int j = 0; j < 4; ++j) {
            float4 v = *(const float4*)&sx[n0 + j][c];
            double vx = (double)v.x, vy = (double)v.y,
                   vz = (double)v.z, vw = (double)v.w;
            acc[j][0] = fma(vx, w0a, acc[j][0]);
            acc[j][0] = fma(vy, w1a, acc[j][0]);
            acc[j][0] = fma(vz, w2a, acc[j][0]);
            acc[j][0] = fma(vw, w3a, acc[j][0]);
            acc[j][1] = fma(vx, w0b, acc[j][1]);
            acc[j][1] = fma(vy, w1b, acc[j][1]);
            acc[j][1] = fma(vz, w2b, acc[j][1]);
            acc[j][1] = fma(vw, w3b, acc[j][1]);
        }
    }
#pragma unroll
    for (int j = 0; j < 4; ++j) {
#pragma unroll
        for (int p = 0; p < 2; ++p) {
            int o = o2 + 16 * p;
            h[(((size_t)(o >> 3)) * NN_ + base + n0 + j) * SW + (o & 7)] = acc[j][p];
        }
    }
}

// ---------------- aggregation: stripe-split, channel-major hd2 -------------
// hd2[oc][s] = h[s][oc]*dis[s] (pre-scale, bit-identical). Channel stride
// 514 doubles -> group lanes hit distinct bank pairs. LDS 54.4 KB -> 3/CU.
__global__ __launch_bounds__(512) void agg_kernel(const double* __restrict__ h,
                                                  const unsigned short* __restrict__ srcl,
                                                  const int* __restrict__ gstart,
                                                  const double* __restrict__ disd,
                                                  const float* __restrict__ bias,
                                                  float* __restrict__ xoutf) {
    __shared__ double hd2[SW * HP];         // 32.9 KB, channel-major
    __shared__ unsigned short ssrc[EG_];    // 16 KB
    __shared__ unsigned short sstart[N_ + 2];  // 1 KB (values <= 8192)
    __shared__ double sdis[N_];             // 4 KB
    int g = blockIdx.x, st = blockIdx.y, tid = threadIdx.x;
    size_t nbase = (size_t)g * N_;

    for (int i = tid; i < EG_; i += 512) ssrc[i] = srcl[(size_t)g * EG_ + i];
    for (int i = tid; i <= N_; i += 512) sstart[i] = (unsigned short)gstart[g * (N_ + 1) + i];
    sdis[tid] = disd[nbase + tid];
    __syncthreads();

    const double* hraw = h + ((size_t)st * NN_ + nbase) * SW;
    for (int i = tid; i < N_ * SW; i += 512) {
        int s = i >> 3, oc = i & 7;
        hd2[oc * HP + s] = hraw[i] * sdis[s];
    }
    __syncthreads();

    int oc = tid & 7, grp = tid >> 3;   // 64 node-groups x 8 channels
    const double* hrow = hd2 + oc * HP;
    double b = (double)bias[st * SW + oc];

    int e0[8], e1[8];
    double a[8];
    int mx = 0;
#pragma unroll
    for (int j = 0; j < 8; ++j) {
        int n = grp + j * 64;
        e0[j] = sstart[n];
        e1[j] = sstart[n + 1];
        a[j] = 0.0;
        int d = e1[j] - e0[j];
        mx = d > mx ? d : mx;
    }
    for (int t = 0; t < mx; ++t) {
#pragma unroll
        for (int j = 0; j < 8; ++j) {
            int idx = e0[j] + t;
            if (idx < e1[j]) {
                int s = ssrc[idx];
                a[j] += hrow[s];
            }
        }
    }
#pragma unroll
    for (int j = 0; j < 8; ++j) {
        int n = grp + j * 64;
        double dn = sdis[n];
        double v = a[j] * dn + hrow[n] * dn + b;
        xoutf[(nbase + n) * HID_ + st * SW + oc] = tanhf((float)v);
    }
}

// ---------------- layer 3 (32 -> 1): fp32 key = round(fp64 tanh) -----------
__global__ __launch_bounds__(512) void gcn3_kernel(const float* __restrict__ xin,
                                                   const float* __restrict__ W2,
                                                   const float* __restrict__ b2,
                                                   const unsigned short* __restrict__ srcl,
                                                   const int* __restrict__ gstart,
                                                   const double* __restrict__ disd,
                                                   float* __restrict__ x3f) {
    __shared__ double h1[N_];
    __shared__ unsigned short ssrc[EG_];
    __shared__ int sstart[N_ + 1];
    __shared__ double sdis[N_];
    int g = blockIdx.x, tid = threadIdx.x;
    size_t nbase = (size_t)g * N_;

    for (int i = tid; i < EG_; i += 512) ssrc[i] = srcl[(size_t)g * EG_ + i];
    for (int i = tid; i <= N_; i += 512) sstart[i] = gstart[g * (N_ + 1) + i];
    int n = tid;
    {
        double a = 0.0;
#pragma unroll
        for (int c = 0; c < HID_; ++c)
            a = fma((double)xin[(nbase + n) * HID_ + c], (double)W2[c], a);
        h1[n] = a;
        sdis[n] = disd[nbase + n];
    }
    __syncthreads();

    int e0 = sstart[n], e1 = sstart[n + 1];
    double a = 0.0;
    for (int e = e0; e < e1; ++e) {
        int s = ssrc[e];
        a += h1[s] * sdis[s];
    }
    double dn = sdis[n];
    double v = a * dn + h1[n] * dn * dn + (double)b2[0];
    x3f[nbase + n] = (float)tanh(v);   // fp32 rank key AND feature value
}

// ---------------- per-graph head: fp32 keys, ulp-window tie -> index -------
__global__ __launch_bounds__(256) void head_kernel(const float* __restrict__ x1,
                                                   const float* __restrict__ x2,
                                                   const float* __restrict__ x3f,
                                                   const float* __restrict__ c1w,
                                                   const float* __restrict__ c1b,
                                                   const float* __restrict__ c2w,
                                                   const float* __restrict__ c2b,
                                                   const float* __restrict__ l1w,
                                                   const float* __restrict__ l1b,
                                                   const float* __restrict__ l2w,
                                                   const float* __restrict__ l2b,
                                                   float* __restrict__ out) {
    int g = blockIdx.x;
    size_t nbase = (size_t)g * N_;
    __shared__ float sv[N_];
    __shared__ int   topk[K_];
    __shared__ float pooled[K_][LAT_];
    __shared__ float c1[16][K_];
    __shared__ float mp[16][10];
    __shared__ float c2[32 * 6];
    __shared__ float l1[128];

    for (int i = threadIdx.x; i < K_; i += 256) topk[i] = i;  // fallback
    for (int i = threadIdx.x; i < N_; i += 256) sv[i] = x3f[nbase + i];
    __syncthreads();

    // top-K descending on fp32 keys; pairs within ~1.5 ulp (relative) are
    // np-fp32 ties -> stable order (lower index first).
    for (int i = threadIdx.x; i < N_; i += 256) {
        float v = sv[i];
        int rank = 0;
        for (int j = 0; j < N_; ++j) {
            float u = sv[j];
            float mag = fmaxf(fabsf(u), fabsf(v));
            bool tie = fabsf(u - v) <= EPS_REL * mag;
            bool beats = tie ? (j < i) : (u > v);
            rank += beats;
        }
        if (rank < K_) topk[rank] = i;
    }
    __syncthreads();

    for (int i = threadIdx.x; i < K_ * LAT_; i += 256) {
        int k = i / LAT_, c = i % LAT_;
        int node = topk[k];
        float f;
        if (c < HID_)            f = x1[(nbase + node) * HID_ + c];
        else if (c < 2 * HID_)   f = x2[(nbase + node) * HID_ + (c - HID_)];
        else                     f = sv[node];
        pooled[k][c] = f;
    }
    __syncthreads();

    for (int i = threadIdx.x; i < 16 * K_; i += 256) {
        int o = i / K_, k = i % K_;
        float acc = c1b[o];
        for (int c = 0; c < LAT_; ++c) acc += pooled[k][c] * c1w[o * LAT_ + c];
        c1[o][k] = fmaxf(acc, 0.f);
    }
    __syncthreads();

    for (int i = threadIdx.x; i < 160; i += 256) {
        int o = i / 10, t = i % 10;
        mp[o][t] = fmaxf(c1[o][2 * t], c1[o][2 * t + 1]);
    }
    __syncthreads();

    for (int i = threadIdx.x; i < 192; i += 256) {
        int o = i / 6, t = i % 6;
        float acc = c2b[o];
        for (int ic = 0; ic < 16; ++ic)
#pragma unroll
            for (int j = 0; j < 5; ++j)
                acc += mp[ic][t + j] * c2w[(o * 16 + ic) * 5 + j];
        c2[o * 6 + t] = fmaxf(acc, 0.f);
    }
    __syncthreads();

    for (int i = threadIdx.x; i < 128; i += 256) {
        float acc = l1b[i];
        for (int c = 0; c < 192; ++c) acc += c2[c] * l1w[c * 128 + i];
        l1[i] = fmaxf(acc, 0.f);
    }
    __syncthreads();

    for (int i = threadIdx.x; i < 2; i += 256) {
        float acc = l2b[i];
        for (int c = 0; c < 128; ++c) acc += l1[c] * l2w[c * 2 + i];
        out[g * 2 + i] = acc;
    }
}

extern "C" void kernel_launch(void* const* d_in, const int* in_sizes, int n_in,
                              void* d_out, int out_size, void* d_ws, size_t ws_size,
                              hipStream_t stream) {
    const float* x   = (const float*)d_in[0];
    const int*   ei  = (const int*)d_in[1];
    const float* W0  = (const float*)d_in[3];
    const float* b0  = (const float*)d_in[4];
    const float* W1  = (const float*)d_in[5];
    const float* b1  = (const float*)d_in[6];
    const float* W2  = (const float*)d_in[7];
    const float* b2  = (const float*)d_in[8];
    const float* c1w = (const float*)d_in[9];
    const float* c1b = (const float*)d_in[10];
    const float* c2w = (const float*)d_in[11];
    const float* c2b = (const float*)d_in[12];
    const float* l1w = (const float*)d_in[13];
    const float* l1b = (const float*)d_in[14];
    const float* l2w = (const float*)d_in[15];
    const float* l2b = (const float*)d_in[16];

    const int* src = ei;
    const int* dst = ei + (size_t)G_ * EG_;

    char* wsb = (char*)d_ws;
    double* h64  = (double*)wsb;                 wsb += (size_t)NN_ * HID_ * 8;     // 64 MiB (stripe-major)
    unsigned short* srcl = (unsigned short*)wsb; wsb += (size_t)G_ * EG_ * 2;       // 8 MiB
    int* gstart = (int*)wsb;                     wsb += (size_t)G_ * (N_ + 1) * 4;  // 1 MiB
    double* disd = (double*)wsb;                 wsb += (size_t)NN_ * 8;            // 2 MiB
    float*  x3f  = (float*)wsb;                  wsb += (size_t)NN_ * 4;            // 1 MiB
    float*  x1f  = (float*)wsb;                  wsb += (size_t)NN_ * HID_ * 4;     // 32 MiB
    float*  x2f  = (float*)wsb;                  wsb += (size_t)NN_ * HID_ * 4;     // 32 MiB

    dim3 agrid(G_, NSTRIPE);
    csr2_kernel<<<G_, 512, 0, stream>>>(src, dst, srcl, gstart, disd);
    mm_kernel<CIN_><<<NN_ / 64, 256, 0, stream>>>(x, W0, h64);
    agg_kernel<<<agrid, 512, 0, stream>>>(h64, srcl, gstart, disd, b0, x1f);
    mm_kernel<HID_><<<NN_ / 64, 256, 0, stream>>>(x1f, W1, h64);
    agg_kernel<<<agrid, 512, 0, stream>>>(h64, srcl, gstart, disd, b1, x2f);
    gcn3_kernel<<<G_, 512, 0, stream>>>(x2f, W2, b2, srcl, gstart, disd, x3f);
    head_kernel<<<G_, 256, 0, stream>>>(x1f, x2f, x3f, c1w, c1b, c2w, c2b,
                                        l1w, l1b, l2w, l2b, (float*)d_out);
}

// Round 17
// 384.933 us; speedup vs baseline: 1.5210x; 1.0140x over previous
//
#include <hip/hip_runtime.h>
#include <math.h>

#define G_ 512
#define N_ 512
#define NN_ (G_*N_)
#define EG_ 8192
#define CIN_ 128
#define HID_ 32
#define K_ 20
#define LAT_ 65
#define NSTRIPE 4
#define SW 8          // channels per stripe
#define HP 513        // hd2 row pitch (doubles)

// relative tie window: ~1.5 ulp of fp32 (2^-23 = 1.19e-7)
#define EPS_REL 1.8e-7f

// ---------------- CSR build v2 + degree-balanced node permutation ----------
__global__ __launch_bounds__(512) void csr2_kernel(const int* __restrict__ src,
                                                   const int* __restrict__ dst,
                                                   unsigned short* __restrict__ srcl,
                                                   int* __restrict__ gstart,
                                                   unsigned short* __restrict__ nperm,
                                                   double* __restrict__ disd) {
    __shared__ int cnt[N_];
    __shared__ int startv[N_];
    __shared__ int tmpv[N_];
    __shared__ int cursor[N_];
    __shared__ unsigned short binE[EG_];
    int g = blockIdx.x, tid = threadIdx.x;
    const int* ds = dst + (size_t)g * EG_;
    const int* ss = src + (size_t)g * EG_;
    int nb = g * N_;

    cnt[tid] = 0;
    __syncthreads();
    for (int e = tid; e < EG_; e += 512) atomicAdd(&cnt[ds[e] - nb], 1);
    __syncthreads();

    // degree-balanced permutation: stable rank by (deg asc, idx asc)
    {
        int mydeg = cnt[tid];
        int rank = 0;
        for (int j = 0; j < N_; ++j) {
            int dj = cnt[j];
            rank += (dj < mydeg) || (dj == mydeg && j < tid);
        }
        nperm[g * N_ + rank] = (unsigned short)tid;
    }

    startv[tid] = cnt[tid];
    __syncthreads();
    for (int off = 1; off < N_; off <<= 1) {
        tmpv[tid] = startv[tid] + (tid >= off ? startv[tid - off] : 0);
        __syncthreads();
        startv[tid] = tmpv[tid];
        __syncthreads();
    }

    int excl = startv[tid] - cnt[tid];
    cursor[tid] = excl;
    gstart[g * (N_ + 1) + tid] = excl;
    if (tid == 0) gstart[g * (N_ + 1) + N_] = EG_;
    disd[nb + tid] = 1.0 / sqrt((double)(cnt[tid] + 1));
    __syncthreads();

    for (int e = tid; e < EG_; e += 512) {
        int d = ds[e] - nb;
        int slot = atomicAdd(&cursor[d], 1);
        binE[slot] = (unsigned short)e;
    }
    __syncthreads();

    {
        int n = cnt[tid];
        for (int i = 1; i < n; ++i) {
            unsigned short key = binE[excl + i];
            int j = i - 1;
            while (j >= 0 && binE[excl + j] > key) {
                binE[excl + j + 1] = binE[excl + j];
                --j;
            }
            binE[excl + j + 1] = key;
        }
    }
    __syncthreads();

    for (int i = tid; i < EG_; i += 512) {
        int e = binE[i];
        srcl[(size_t)g * EG_ + i] = (unsigned short)(ss[e] - nb);
    }
}

// ---------------- matmul: h[n][o] = sum_c x[n][c]*W[c][o], fp64 acc --------
// 64 nodes/block, 256 threads: thread = (q = tid>>4 -> 4 nodes, o2 = tid&15
// -> channels o2 and o2+16). 8 indep fp64 chains/thread; c-ascending fma
// per chain (bit-identical). Writes h stripe-major.
template <int CI>
__global__ __launch_bounds__(256) void mm_kernel(const float* __restrict__ xin,
                                                 const float* __restrict__ W,
                                                 double* __restrict__ h) {
    __shared__ float sx[64][CI + 4];     // CI=128: 33.8 KB ; CI=32: 9.2 KB
    __shared__ float sW[CI][HID_];       // CI=128: 16 KB ; CI=32: 4 KB
    int tid = threadIdx.x;
    for (int i = tid; i < CI * HID_; i += 256) sW[i / HID_][i % HID_] = W[i];
    size_t base = (size_t)blockIdx.x * 64;
    const float4* xsrc = (const float4*)(xin + base * CI);
    for (int i = tid; i < 64 * CI / 4; i += 256) {
        int row = i / (CI / 4), col = (i % (CI / 4)) * 4;
        *(float4*)&sx[row][col] = xsrc[i];
    }
    __syncthreads();

    int o2 = tid & 15, q = tid >> 4;     // 16 q-groups x 4 nodes
    int n0 = q * 4;
    double acc[4][2];
#pragma unroll
    for (int j = 0; j < 4; ++j) { acc[j][0] = 0.0; acc[j][1] = 0.0; }

    for (int c = 0; c < CI; c += 4) {
        double w0a = (double)sW[c][o2],     w0b = (double)sW[c][o2 + 16];
        double w1a = (double)sW[c + 1][o2], w1b = (double)sW[c + 1][o2 + 16];
        double w2a = (double)sW[c + 2][o2], w2b = (double)sW[c + 2][o2 + 16];
        double w3a = (double)sW[c + 3][o2], w3b = (double)sW[c + 3][o2 + 16];
#pragma unroll
        for (int j = 0; j < 4; ++j) {
            float4 v = *(const float4*)&sx[n0 + j][c];
            double vx = (double)v.x, vy = (double)v.y,
                   vz = (double)v.z, vw = (double)v.w;
            acc[j][0] = fma(vx, w0a, acc[j][0]);
            acc[j][0] = fma(vy, w1a, acc[j][0]);
            acc[j][0] = fma(vz, w2a, acc[j][0]);
            acc[j][0] = fma(vw, w3a, acc[j][0]);
            acc[j][1] = fma(vx, w0b, acc[j][1]);
            acc[j][1] = fma(vy, w1b, acc[j][1]);
            acc[j][1] = fma(vz, w2b, acc[j][1]);
            acc[j][1] = fma(vw, w3b, acc[j][1]);
        }
    }
#pragma unroll
    for (int j = 0; j < 4; ++j) {
#pragma unroll
        for (int p = 0; p < 2; ++p) {
            int o = o2 + 16 * p;
            h[(((size_t)(o >> 3)) * NN_ + base + n0 + j) * SW + (o & 7)] = acc[j][p];
        }
    }
}

// ---------------- aggregation: stripe-split, degree-balanced ---------------
// Thread grp handles nodes nperm[grp*8..grp*8+7] (similar degree -> minimal
// predication waste). Per-node CSR order preserved -> bit-identical sums.
__global__ __launch_bounds__(512) void agg_kernel(const double* __restrict__ h,
                                                  const unsigned short* __restrict__ srcl,
                                                  const int* __restrict__ gstart,
                                                  const unsigned short* __restrict__ nperm,
                                                  const double* __restrict__ disd,
                                                  const float* __restrict__ bias,
                                                  float* __restrict__ xoutf) {
    __shared__ double hd2[SW * HP];            // 32.8 KB, channel-major
    __shared__ unsigned short ssrc[EG_];       // 16 KB
    __shared__ unsigned short sstart[N_ + 2];  // 1 KB
    __shared__ unsigned short sperm[N_];       // 1 KB
    int g = blockIdx.x, st = blockIdx.y, tid = threadIdx.x;
    size_t nbase = (size_t)g * N_;

    for (int i = tid; i < EG_; i += 512) ssrc[i] = srcl[(size_t)g * EG_ + i];
    for (int i = tid; i <= N_; i += 512) sstart[i] = (unsigned short)gstart[g * (N_ + 1) + i];
    sperm[tid] = nperm[g * N_ + tid];
    __syncthreads();

    const double* hraw = h + ((size_t)st * NN_ + nbase) * SW;
    const double* dg = disd + nbase;
    for (int i = tid; i < N_ * SW; i += 512) {
        int s = i >> 3, oc = i & 7;
        hd2[oc * HP + s] = hraw[i] * dg[s];
    }
    __syncthreads();

    int oc = tid & 7, grp = tid >> 3;   // 64 node-groups x 8 channels
    const double* hrow = hd2 + oc * HP;
    double b = (double)bias[st * SW + oc];

    int nn[8], e0[8], e1[8];
    double a[8];
    int mx = 0;
#pragma unroll
    for (int j = 0; j < 8; ++j) {
        int n = sperm[grp * 8 + j];
        nn[j] = n;
        e0[j] = sstart[n];
        e1[j] = sstart[n + 1];
        a[j] = 0.0;
        int d = e1[j] - e0[j];
        mx = d > mx ? d : mx;
    }
    for (int t = 0; t < mx; ++t) {
#pragma unroll
        for (int j = 0; j < 8; ++j) {
            int idx = e0[j] + t;
            if (idx < e1[j]) {
                int s = ssrc[idx];
                a[j] += hrow[s];
            }
        }
    }
#pragma unroll
    for (int j = 0; j < 8; ++j) {
        int n = nn[j];
        double dn = dg[n];
        double v = a[j] * dn + hrow[n] * dn + b;
        xoutf[(nbase + n) * HID_ + st * SW + oc] = tanhf((float)v);
    }
}

// ---------------- layer 3 (32 -> 1): fp32 key = round(fp64 tanh) -----------
__global__ __launch_bounds__(512) void gcn3_kernel(const float* __restrict__ xin,
                                                   const float* __restrict__ W2,
                                                   const float* __restrict__ b2,
                                                   const unsigned short* __restrict__ srcl,
                                                   const int* __restrict__ gstart,
                                                   const double* __restrict__ disd,
                                                   float* __restrict__ x3f) {
    __shared__ double h1[N_];
    __shared__ unsigned short ssrc[EG_];
    __shared__ int sstart[N_ + 1];
    __shared__ double sdis[N_];
    int g = blockIdx.x, tid = threadIdx.x;
    size_t nbase = (size_t)g * N_;

    for (int i = tid; i < EG_; i += 512) ssrc[i] = srcl[(size_t)g * EG_ + i];
    for (int i = tid; i <= N_; i += 512) sstart[i] = gstart[g * (N_ + 1) + i];
    int n = tid;
    {
        double a = 0.0;
#pragma unroll
        for (int c = 0; c < HID_; ++c)
            a = fma((double)xin[(nbase + n) * HID_ + c], (double)W2[c], a);
        h1[n] = a;
        sdis[n] = disd[nbase + n];
    }
    __syncthreads();

    int e0 = sstart[n], e1 = sstart[n + 1];
    double a = 0.0;
    for (int e = e0; e < e1; ++e) {
        int s = ssrc[e];
        a += h1[s] * sdis[s];
    }
    double dn = sdis[n];
    double v = a * dn + h1[n] * dn * dn + (double)b2[0];
    x3f[nbase + n] = (float)tanh(v);   // fp32 rank key AND feature value
}

// ---------------- per-graph head: fp32 keys, ulp-window tie -> index -------
__global__ __launch_bounds__(256) void head_kernel(const float* __restrict__ x1,
                                                   const float* __restrict__ x2,
                                                   const float* __restrict__ x3f,
                                                   const float* __restrict__ c1w,
                                                   const float* __restrict__ c1b,
                                                   const float* __restrict__ c2w,
                                                   const float* __restrict__ c2b,
                                                   const float* __restrict__ l1w,
                                                   const float* __restrict__ l1b,
                                                   const float* __restrict__ l2w,
                                                   const float* __restrict__ l2b,
                                                   float* __restrict__ out) {
    int g = blockIdx.x;
    size_t nbase = (size_t)g * N_;
    __shared__ float sv[N_];
    __shared__ int   topk[K_];
    __shared__ float pooled[K_][LAT_];
    __shared__ float c1[16][K_];
    __shared__ float mp[16][10];
    __shared__ float c2[32 * 6];
    __shared__ float l1[128];

    for (int i = threadIdx.x; i < K_; i += 256) topk[i] = i;  // fallback
    for (int i = threadIdx.x; i < N_; i += 256) sv[i] = x3f[nbase + i];
    __syncthreads();

    // top-K descending on fp32 keys; pairs within ~1.5 ulp (relative) are
    // np-fp32 ties -> stable order (lower index first).
    for (int i = threadIdx.x; i < N_; i += 256) {
        float v = sv[i];
        int rank = 0;
        for (int j = 0; j < N_; ++j) {
            float u = sv[j];
            float mag = fmaxf(fabsf(u), fabsf(v));
            bool tie = fabsf(u - v) <= EPS_REL * mag;
            bool beats = tie ? (j < i) : (u > v);
            rank += beats;
        }
        if (rank < K_) topk[rank] = i;
    }
    __syncthreads();

    for (int i = threadIdx.x; i < K_ * LAT_; i += 256) {
        int k = i / LAT_, c = i % LAT_;
        int node = topk[k];
        float f;
        if (c < HID_)            f = x1[(nbase + node) * HID_ + c];
        else if (c < 2 * HID_)   f = x2[(nbase + node) * HID_ + (c - HID_)];
        else                     f = sv[node];
        pooled[k][c] = f;
    }
    __syncthreads();

    for (int i = threadIdx.x; i < 16 * K_; i += 256) {
        int o = i / K_, k = i % K_;
        float acc = c1b[o];
        for (int c = 0; c < LAT_; ++c) acc += pooled[k][c] * c1w[o * LAT_ + c];
        c1[o][k] = fmaxf(acc, 0.f);
    }
    __syncthreads();

    for (int i = threadIdx.x; i < 160; i += 256) {
        int o = i / 10, t = i % 10;
        mp[o][t] = fmaxf(c1[o][2 * t], c1[o][2 * t + 1]);
    }
    __syncthreads();

    for (int i = threadIdx.x; i < 192; i += 256) {
        int o = i / 6, t = i % 6;
        float acc = c2b[o];
        for (int ic = 0; ic < 16; ++ic)
#pragma unroll
            for (int j = 0; j < 5; ++j)
                acc += mp[ic][t + j] * c2w[(o * 16 + ic) * 5 + j];
        c2[o * 6 + t] = fmaxf(acc, 0.f);
    }
    __syncthreads();

    for (int i = threadIdx.x; i < 128; i += 256) {
        float acc = l1b[i];
        for (int c = 0; c < 192; ++c) acc += c2[c] * l1w[c * 128 + i];
        l1[i] = fmaxf(acc, 0.f);
    }
    __syncthreads();

    for (int i = threadIdx.x; i < 2; i += 256) {
        float acc = l2b[i];
        for (int c = 0; c < 128; ++c) acc += l1[c] * l2w[c * 2 + i];
        out[g * 2 + i] = acc;
    }
}

extern "C" void kernel_launch(void* const* d_in, const int* in_sizes, int n_in,
                              void* d_out, int out_size, void* d_ws, size_t ws_size,
                              hipStream_t stream) {
    const float* x   = (const float*)d_in[0];
    const int*   ei  = (const int*)d_in[1];
    const float* W0  = (const float*)d_in[3];
    const float* b0  = (const float*)d_in[4];
    const float* W1  = (const float*)d_in[5];
    const float* b1  = (const float*)d_in[6];
    const float* W2  = (const float*)d_in[7];
    const float* b2  = (const float*)d_in[8];
    const float* c1w = (const float*)d_in[9];
    const float* c1b = (const float*)d_in[10];
    const float* c2w = (const float*)d_in[11];
    const float* c2b = (const float*)d_in[12];
    const float* l1w = (const float*)d_in[13];
    const float* l1b = (const float*)d_in[14];
    const float* l2w = (const float*)d_in[15];
    const float* l2b = (const float*)d_in[16];

    const int* src = ei;
    const int* dst = ei + (size_t)G_ * EG_;

    char* wsb = (char*)d_ws;
    double* h64  = (double*)wsb;                 wsb += (size_t)NN_ * HID_ * 8;     // 64 MiB (stripe-major)
    unsigned short* srcl = (unsigned short*)wsb; wsb += (size_t)G_ * EG_ * 2;       // 8 MiB
    int* gstart = (int*)wsb;                     wsb += (size_t)G_ * (N_ + 1) * 4;  // 1 MiB
    unsigned short* nperm = (unsigned short*)wsb; wsb += (size_t)G_ * N_ * 2;       // 0.5 MiB
    double* disd = (double*)wsb;                 wsb += (size_t)NN_ * 8;            // 2 MiB
    float*  x3f  = (float*)wsb;                  wsb += (size_t)NN_ * 4;            // 1 MiB
    float*  x1f  = (float*)wsb;                  wsb += (size_t)NN_ * HID_ * 4;     // 32 MiB
    float*  x2f  = (float*)wsb;                  wsb += (size_t)NN_ * HID_ * 4;     // 32 MiB

    dim3 agrid(G_, NSTRIPE);
    csr2_kernel<<<G_, 512, 0, stream>>>(src, dst, srcl, gstart, nperm, disd);
    mm_kernel<CIN_><<<NN_ / 64, 256, 0, stream>>>(x, W0, h64);
    agg_kernel<<<agrid, 512, 0, stream>>>(h64, srcl, gstart, nperm, disd, b0, x1f);
    mm_kernel<HID_><<<NN_ / 64, 256, 0, stream>>>(x1f, W1, h64);
    agg_kernel<<<agrid, 512, 0, stream>>>(h64, srcl, gstart, nperm, disd, b1, x2f);
    gcn3_kernel<<<G_, 512, 0, stream>>>(x2f, W2, b2, srcl, gstart, disd, x3f);
    head_kernel<<<G_, 256, 0, stream>>>(x1f, x2f, x3f, c1w, c1b, c2w, c2b,
                                        l1w, l1b, l2w, l2b, (float*)d_out);
}

// Round 18
// 371.361 us; speedup vs baseline: 1.5766x; 1.0365x over previous
//
#include <hip/hip_runtime.h>
#include <math.h>

#define G_ 512
#define N_ 512
#define NN_ (G_*N_)
#define EG_ 8192
#define EGP 8704      // padded edge capacity per graph (even-padded bins)
#define CIN_ 128
#define HID_ 32
#define K_ 20
#define LAT_ 65
#define NSTRIPE 4
#define SW 8          // channels per stripe
#define HP 513        // hd2 row pitch (doubles); slot 512 = sentinel -0.0

// relative tie window: ~1.5 ulp of fp32 (2^-23 = 1.19e-7)
#define EPS_REL 1.8e-7f

// ---------------- CSR build v3: even-padded bins + sentinel ----------------
__global__ __launch_bounds__(512) void csr2_kernel(const int* __restrict__ src,
                                                   const int* __restrict__ dst,
                                                   unsigned short* __restrict__ srcl,
                                                   int* __restrict__ gstart,
                                                   unsigned short* __restrict__ nperm,
                                                   double* __restrict__ disd) {
    __shared__ int cnt[N_];
    __shared__ int startv[N_];
    __shared__ int tmpv[N_];
    __shared__ int cursor[N_];
    __shared__ unsigned short binE[EGP];   // 17 KB, 0xFFFF = hole
    int g = blockIdx.x, tid = threadIdx.x;
    const int* ds = dst + (size_t)g * EG_;
    const int* ss = src + (size_t)g * EG_;
    int nb = g * N_;

    cnt[tid] = 0;
    for (int i = tid; i < EGP; i += 512) binE[i] = 0xFFFF;
    __syncthreads();
    for (int e = tid; e < EG_; e += 512) atomicAdd(&cnt[ds[e] - nb], 1);
    __syncthreads();

    // degree-balanced permutation: stable rank by (deg asc, idx asc)
    {
        int mydeg = cnt[tid];
        int rank = 0;
        for (int j = 0; j < N_; ++j) {
            int dj = cnt[j];
            rank += (dj < mydeg) || (dj == mydeg && j < tid);
        }
        nperm[g * N_ + rank] = (unsigned short)tid;
    }

    int pc = (cnt[tid] + 1) & ~1;          // even-padded bin size
    startv[tid] = pc;
    __syncthreads();
    for (int off = 1; off < N_; off <<= 1) {
        tmpv[tid] = startv[tid] + (tid >= off ? startv[tid - off] : 0);
        __syncthreads();
        startv[tid] = tmpv[tid];
        __syncthreads();
    }

    int excl = startv[tid] - pc;
    cursor[tid] = excl;
    gstart[g * (N_ + 1) + tid] = excl;
    if (tid == 511) gstart[g * (N_ + 1) + N_] = startv[511];
    disd[nb + tid] = 1.0 / sqrt((double)(cnt[tid] + 1));
    __syncthreads();

    for (int e = tid; e < EG_; e += 512) {
        int d = ds[e] - nb;
        int slot = atomicAdd(&cursor[d], 1);
        binE[slot] = (unsigned short)e;
    }
    __syncthreads();

    {   // canonicalize own bin: insertion sort by edge id (original order)
        int n = cnt[tid];
        for (int i = 1; i < n; ++i) {
            unsigned short key = binE[excl + i];
            int j = i - 1;
            while (j >= 0 && binE[excl + j] > key) {
                binE[excl + j + 1] = binE[excl + j];
                --j;
            }
            binE[excl + j + 1] = key;
        }
    }
    __syncthreads();

    for (int i = tid; i < EGP; i += 512) {
        unsigned short e = binE[i];
        srcl[(size_t)g * EGP + i] =
            (e == 0xFFFF) ? (unsigned short)N_ : (unsigned short)(ss[e] - nb);
    }
}

// ---------------- matmul: h[n][o] = sum_c x[n][c]*W[c][o], fp64 acc --------
// 64 nodes/block, 256 threads; 8 indep fp64 chains/thread; c-ascending fma
// per chain (bit-identical). Writes h stripe-major.
template <int CI>
__global__ __launch_bounds__(256) void mm_kernel(const float* __restrict__ xin,
                                                 const float* __restrict__ W,
                                                 double* __restrict__ h) {
    __shared__ float sx[64][CI + 4];     // CI=128: 33.8 KB ; CI=32: 9.2 KB
    __shared__ float sW[CI][HID_];       // CI=128: 16 KB ; CI=32: 4 KB
    int tid = threadIdx.x;
    for (int i = tid; i < CI * HID_; i += 256) sW[i / HID_][i % HID_] = W[i];
    size_t base = (size_t)blockIdx.x * 64;
    const float4* xsrc = (const float4*)(xin + base * CI);
    for (int i = tid; i < 64 * CI / 4; i += 256) {
        int row = i / (CI / 4), col = (i % (CI / 4)) * 4;
        *(float4*)&sx[row][col] = xsrc[i];
    }
    __syncthreads();

    int o2 = tid & 15, q = tid >> 4;     // 16 q-groups x 4 nodes
    int n0 = q * 4;
    double acc[4][2];
#pragma unroll
    for (int j = 0; j < 4; ++j) { acc[j][0] = 0.0; acc[j][1] = 0.0; }

    for (int c = 0; c < CI; c += 4) {
        double w0a = (double)sW[c][o2],     w0b = (double)sW[c][o2 + 16];
        double w1a = (double)sW[c + 1][o2], w1b = (double)sW[c + 1][o2 + 16];
        double w2a = (double)sW[c + 2][o2], w2b = (double)sW[c + 2][o2 + 16];
        double w3a = (double)sW[c + 3][o2], w3b = (double)sW[c + 3][o2 + 16];
#pragma unroll
        for (int j = 0; j < 4; ++j) {
            float4 v = *(const float4*)&sx[n0 + j][c];
            double vx = (double)v.x, vy = (double)v.y,
                   vz = (double)v.z, vw = (double)v.w;
            acc[j][0] = fma(vx, w0a, acc[j][0]);
            acc[j][0] = fma(vy, w1a, acc[j][0]);
            acc[j][0] = fma(vz, w2a, acc[j][0]);
            acc[j][0] = fma(vw, w3a, acc[j][0]);
            acc[j][1] = fma(vx, w0b, acc[j][1]);
            acc[j][1] = fma(vy, w1b, acc[j][1]);
            acc[j][1] = fma(vz, w2b, acc[j][1]);
            acc[j][1] = fma(vw, w3b, acc[j][1]);
        }
    }
#pragma unroll
    for (int j = 0; j < 4; ++j) {
#pragma unroll
        for (int p = 0; p < 2; ++p) {
            int o = o2 + 16 * p;
            h[(((size_t)(o >> 3)) * NN_ + base + n0 + j) * SW + (o & 7)] = acc[j][p];
        }
    }
}

// ---------------- aggregation: paired edges, degree-balanced ---------------
// Bins even-padded with sentinel s=512 (hd2 slot = -0.0: x + -0.0 == x
// bitwise for all x). Two edges per iteration via one u32 read; adds stay
// sequential in CSR order -> bit-identical sums.
__global__ __launch_bounds__(512) void agg_kernel(const double* __restrict__ h,
                                                  const unsigned short* __restrict__ srcl,
                                                  const int* __restrict__ gstart,
                                                  const unsigned short* __restrict__ nperm,
                                                  const double* __restrict__ disd,
                                                  const float* __restrict__ bias,
                                                  float* __restrict__ xoutf) {
    __shared__ double hd2[SW * HP];            // 32.8 KB, channel-major
    __shared__ unsigned short ssrc[EGP];       // 17.4 KB
    __shared__ unsigned short sstart[N_ + 2];  // 1 KB
    __shared__ unsigned short sperm[N_];       // 1 KB
    int g = blockIdx.x, st = blockIdx.y, tid = threadIdx.x;
    size_t nbase = (size_t)g * N_;

    for (int i = tid; i < EGP; i += 512) ssrc[i] = srcl[(size_t)g * EGP + i];
    for (int i = tid; i <= N_; i += 512) sstart[i] = (unsigned short)gstart[g * (N_ + 1) + i];
    sperm[tid] = nperm[g * N_ + tid];
    __syncthreads();

    const double* hraw = h + ((size_t)st * NN_ + nbase) * SW;
    const double* dg = disd + nbase;
    for (int i = tid; i < N_ * SW; i += 512) {
        int s = i >> 3, oc = i & 7;
        hd2[oc * HP + s] = hraw[i] * dg[s];
    }
    if (tid < SW) hd2[tid * HP + N_] = -0.0;   // sentinel
    __syncthreads();

    int oc = tid & 7, grp = tid >> 3;   // 64 node-groups x 8 channels
    const double* hrow = hd2 + oc * HP;
    const unsigned int* ssrc32 = (const unsigned int*)ssrc;
    double b = (double)bias[st * SW + oc];

    int nn[8], e0h[8], e1h[8];
    double a[8];
    int mx = 0;
#pragma unroll
    for (int j = 0; j < 8; ++j) {
        int n = sperm[grp * 8 + j];
        nn[j] = n;
        e0h[j] = sstart[n] >> 1;
        e1h[j] = sstart[n + 1] >> 1;
        a[j] = 0.0;
        int d = e1h[j] - e0h[j];
        mx = d > mx ? d : mx;
    }
    for (int t = 0; t < mx; ++t) {
#pragma unroll
        for (int j = 0; j < 8; ++j) {
            int idx = e0h[j] + t;
            if (idx < e1h[j]) {
                unsigned int pr = ssrc32[idx];
                a[j] += hrow[pr & 0xFFFFu];
                a[j] += hrow[pr >> 16];
            }
        }
    }
#pragma unroll
    for (int j = 0; j < 8; ++j) {
        int n = nn[j];
        double dn = dg[n];
        double v = a[j] * dn + hrow[n] * dn + b;
        xoutf[(nbase + n) * HID_ + st * SW + oc] = tanhf((float)v);
    }
}

// ---------------- layer 3 (32 -> 1): fp32 key = round(fp64 tanh) -----------
__global__ __launch_bounds__(512) void gcn3_kernel(const float* __restrict__ xin,
                                                   const float* __restrict__ W2,
                                                   const float* __restrict__ b2,
                                                   const unsigned short* __restrict__ srcl,
                                                   const int* __restrict__ gstart,
                                                   const double* __restrict__ disd,
                                                   float* __restrict__ x3f) {
    __shared__ double h1[N_ + 1];
    __shared__ unsigned short ssrc[EGP];
    __shared__ int sstart[N_ + 1];
    __shared__ double sdis[N_ + 1];
    int g = blockIdx.x, tid = threadIdx.x;
    size_t nbase = (size_t)g * N_;

    for (int i = tid; i < EGP; i += 512) ssrc[i] = srcl[(size_t)g * EGP + i];
    for (int i = tid; i <= N_; i += 512) sstart[i] = gstart[g * (N_ + 1) + i];
    if (tid == 0) { h1[N_] = -0.0; sdis[N_] = 1.0; }   // sentinel term: -0.0
    int n = tid;
    {
        double a = 0.0;
#pragma unroll
        for (int c = 0; c < HID_; ++c)
            a = fma((double)xin[(nbase + n) * HID_ + c], (double)W2[c], a);
        h1[n] = a;
        sdis[n] = disd[nbase + n];
    }
    __syncthreads();

    int e0 = sstart[n], e1 = sstart[n + 1];
    double a = 0.0;
    for (int e = e0; e < e1; ++e) {
        int s = ssrc[e];
        a += h1[s] * sdis[s];
    }
    double dn = sdis[n];
    double v = a * dn + h1[n] * dn * dn + (double)b2[0];
    x3f[nbase + n] = (float)tanh(v);   // fp32 rank key AND feature value
}

// ---------------- per-graph head: fp32 keys, ulp-window tie -> index -------
__global__ __launch_bounds__(256) void head_kernel(const float* __restrict__ x1,
                                                   const float* __restrict__ x2,
                                                   const float* __restrict__ x3f,
                                                   const float* __restrict__ c1w,
                                                   const float* __restrict__ c1b,
                                                   const float* __restrict__ c2w,
                                                   const float* __restrict__ c2b,
                                                   const float* __restrict__ l1w,
                                                   const float* __restrict__ l1b,
                                                   const float* __restrict__ l2w,
                                                   const float* __restrict__ l2b,
                                                   float* __restrict__ out) {
    int g = blockIdx.x;
    size_t nbase = (size_t)g * N_;
    __shared__ float sv[N_];
    __shared__ int   topk[K_];
    __shared__ float pooled[K_][LAT_];
    __shared__ float c1[16][K_];
    __shared__ float mp[16][10];
    __shared__ float c2[32 * 6];
    __shared__ float l1[128];

    for (int i = threadIdx.x; i < K_; i += 256) topk[i] = i;  // fallback
    for (int i = threadIdx.x; i < N_; i += 256) sv[i] = x3f[nbase + i];
    __syncthreads();

    // top-K descending on fp32 keys; pairs within ~1.5 ulp (relative) are
    // np-fp32 ties -> stable order (lower index first).
    for (int i = threadIdx.x; i < N_; i += 256) {
        float v = sv[i];
        int rank = 0;
        for (int j = 0; j < N_; ++j) {
            float u = sv[j];
            float mag = fmaxf(fabsf(u), fabsf(v));
            bool tie = fabsf(u - v) <= EPS_REL * mag;
            bool beats = tie ? (j < i) : (u > v);
            rank += beats;
        }
        if (rank < K_) topk[rank] = i;
    }
    __syncthreads();

    for (int i = threadIdx.x; i < K_ * LAT_; i += 256) {
        int k = i / LAT_, c = i % LAT_;
        int node = topk[k];
        float f;
        if (c < HID_)            f = x1[(nbase + node) * HID_ + c];
        else if (c < 2 * HID_)   f = x2[(nbase + node) * HID_ + (c - HID_)];
        else                     f = sv[node];
        pooled[k][c] = f;
    }
    __syncthreads();

    for (int i = threadIdx.x; i < 16 * K_; i += 256) {
        int o = i / K_, k = i % K_;
        float acc = c1b[o];
        for (int c = 0; c < LAT_; ++c) acc += pooled[k][c] * c1w[o * LAT_ + c];
        c1[o][k] = fmaxf(acc, 0.f);
    }
    __syncthreads();

    for (int i = threadIdx.x; i < 160; i += 256) {
        int o = i / 10, t = i % 10;
        mp[o][t] = fmaxf(c1[o][2 * t], c1[o][2 * t + 1]);
    }
    __syncthreads();

    for (int i = threadIdx.x; i < 192; i += 256) {
        int o = i / 6, t = i % 6;
        float acc = c2b[o];
        for (int ic = 0; ic < 16; ++ic)
#pragma unroll
            for (int j = 0; j < 5; ++j)
                acc += mp[ic][t + j] * c2w[(o * 16 + ic) * 5 + j];
        c2[o * 6 + t] = fmaxf(acc, 0.f);
    }
    __syncthreads();

    for (int i = threadIdx.x; i < 128; i += 256) {
        float acc = l1b[i];
        for (int c = 0; c < 192; ++c) acc += c2[c] * l1w[c * 128 + i];
        l1[i] = fmaxf(acc, 0.f);
    }
    __syncthreads();

    for (int i = threadIdx.x; i < 2; i += 256) {
        float acc = l2b[i];
        for (int c = 0; c < 128; ++c) acc += l1[c] * l2w[c * 2 + i];
        out[g * 2 + i] = acc;
    }
}

extern "C" void kernel_launch(void* const* d_in, const int* in_sizes, int n_in,
                              void* d_out, int out_size, void* d_ws, size_t ws_size,
                              hipStream_t stream) {
    const float* x   = (const float*)d_in[0];
    const int*   ei  = (const int*)d_in[1];
    const float* W0  = (const float*)d_in[3];
    const float* b0  = (const float*)d_in[4];
    const float* W1  = (const float*)d_in[5];
    const float* b1  = (const float*)d_in[6];
    const float* W2  = (const float*)d_in[7];
    const float* b2  = (const float*)d_in[8];
    const float* c1w = (const float*)d_in[9];
    const float* c1b = (const float*)d_in[10];
    const float* c2w = (const float*)d_in[11];
    const float* c2b = (const float*)d_in[12];
    const float* l1w = (const float*)d_in[13];
    const float* l1b = (const float*)d_in[14];
    const float* l2w = (const float*)d_in[15];
    const float* l2b = (const float*)d_in[16];

    const int* src = ei;
    const int* dst = ei + (size_t)G_ * EG_;

    char* wsb = (char*)d_ws;
    double* h64  = (double*)wsb;                 wsb += (size_t)NN_ * HID_ * 8;     // 64 MiB (stripe-major)
    unsigned short* srcl = (unsigned short*)wsb; wsb += (size_t)G_ * EGP * 2;       // 8.5 MiB
    int* gstart = (int*)wsb;                     wsb += (size_t)G_ * (N_ + 1) * 4;  // 1 MiB
    unsigned short* nperm = (unsigned short*)wsb; wsb += (size_t)G_ * N_ * 2;       // 0.5 MiB
    double* disd = (double*)wsb;                 wsb += (size_t)NN_ * 8;            // 2 MiB
    float*  x3f  = (float*)wsb;                  wsb += (size_t)NN_ * 4;            // 1 MiB
    float*  x1f  = (float*)wsb;                  wsb += (size_t)NN_ * HID_ * 4;     // 32 MiB
    float*  x2f  = (float*)wsb;                  wsb += (size_t)NN_ * HID_ * 4;     // 32 MiB

    dim3 agrid(G_, NSTRIPE);
    csr2_kernel<<<G_, 512, 0, stream>>>(src, dst, srcl, gstart, nperm, disd);
    mm_kernel<CIN_><<<NN_ / 64, 256, 0, stream>>>(x, W0, h64);
    agg_kernel<<<agrid, 512, 0, stream>>>(h64, srcl, gstart, nperm, disd, b0, x1f);
    mm_kernel<HID_><<<NN_ / 64, 256, 0, stream>>>(x1f, W1, h64);
    agg_kernel<<<agrid, 512, 0, stream>>>(h64, srcl, gstart, nperm, disd, b1, x2f);
    gcn3_kernel<<<G_, 512, 0, stream>>>(x2f, W2, b2, srcl, gstart, disd, x3f);
    head_kernel<<<G_, 256, 0, stream>>>(x1f, x2f, x3f, c1w, c1b, c2w, c2b,
                                        l1w, l1b, l2w, l2b, (float*)d_out);
}

// Round 19
// 370.740 us; speedup vs baseline: 1.5793x; 1.0017x over previous
//
#include <hip/hip_runtime.h>
#include <math.h>

#define G_ 512
#define N_ 512
#define NN_ (G_*N_)
#define EG_ 8192
#define EGP 8704      // padded edge capacity per graph (even-padded bins)
#define CIN_ 128
#define HID_ 32
#define K_ 20
#define LAT_ 65
#define NSTRIPE 4
#define SW 8          // channels per stripe
#define HP 513        // hd2 row pitch (doubles); slot 512 = sentinel -0.0

// relative tie window: ~1.5 ulp of fp32 (2^-23 = 1.19e-7)
#define EPS_REL 1.8e-7f

// ---------------- CSR build v3: even-padded bins + sentinel ----------------
__global__ __launch_bounds__(512) void csr2_kernel(const int* __restrict__ src,
                                                   const int* __restrict__ dst,
                                                   unsigned short* __restrict__ srcl,
                                                   int* __restrict__ gstart,
                                                   unsigned short* __restrict__ nperm,
                                                   double* __restrict__ disd) {
    __shared__ int cnt[N_];
    __shared__ int startv[N_];
    __shared__ int tmpv[N_];
    __shared__ int cursor[N_];
    __shared__ unsigned short binE[EGP];   // 17 KB, 0xFFFF = hole
    int g = blockIdx.x, tid = threadIdx.x;
    const int* ds = dst + (size_t)g * EG_;
    const int* ss = src + (size_t)g * EG_;
    int nb = g * N_;

    cnt[tid] = 0;
    for (int i = tid; i < EGP; i += 512) binE[i] = 0xFFFF;
    __syncthreads();
    for (int e = tid; e < EG_; e += 512) atomicAdd(&cnt[ds[e] - nb], 1);
    __syncthreads();

    // degree-balanced permutation: stable rank by (deg asc, idx asc)
    {
        int mydeg = cnt[tid];
        int rank = 0;
        for (int j = 0; j < N_; ++j) {
            int dj = cnt[j];
            rank += (dj < mydeg) || (dj == mydeg && j < tid);
        }
        nperm[g * N_ + rank] = (unsigned short)tid;
    }

    int pc = (cnt[tid] + 1) & ~1;          // even-padded bin size
    startv[tid] = pc;
    __syncthreads();
    for (int off = 1; off < N_; off <<= 1) {
        tmpv[tid] = startv[tid] + (tid >= off ? startv[tid - off] : 0);
        __syncthreads();
        startv[tid] = tmpv[tid];
        __syncthreads();
    }

    int excl = startv[tid] - pc;
    cursor[tid] = excl;
    gstart[g * (N_ + 1) + tid] = excl;
    if (tid == 511) gstart[g * (N_ + 1) + N_] = startv[511];
    disd[nb + tid] = 1.0 / sqrt((double)(cnt[tid] + 1));
    __syncthreads();

    for (int e = tid; e < EG_; e += 512) {
        int d = ds[e] - nb;
        int slot = atomicAdd(&cursor[d], 1);
        binE[slot] = (unsigned short)e;
    }
    __syncthreads();

    {   // canonicalize own bin: insertion sort by edge id (original order)
        int n = cnt[tid];
        for (int i = 1; i < n; ++i) {
            unsigned short key = binE[excl + i];
            int j = i - 1;
            while (j >= 0 && binE[excl + j] > key) {
                binE[excl + j + 1] = binE[excl + j];
                --j;
            }
            binE[excl + j + 1] = key;
        }
    }
    __syncthreads();

    for (int i = tid; i < EGP; i += 512) {
        unsigned short e = binE[i];
        srcl[(size_t)g * EGP + i] =
            (e == 0xFFFF) ? (unsigned short)N_ : (unsigned short)(ss[e] - nb);
    }
}

// ---------------- matmul: h[n][o] = sum_c x[n][c]*W[c][o], fp64 acc --------
// 64 nodes/block, 256 threads; 8 indep fp64 chains/thread; c-ascending fma
// per chain (bit-identical). W TRANSPOSED in LDS -> float4 reads (6 b128
// LDS reads per c-group instead of 12 mixed). Writes h stripe-major.
template <int CI>
__global__ __launch_bounds__(256) void mm_kernel(const float* __restrict__ xin,
                                                 const float* __restrict__ W,
                                                 double* __restrict__ h) {
    __shared__ float sx[64][CI + 4];      // CI=128: 33.8 KB ; CI=32: 9.2 KB
    __shared__ float sWt[HID_][CI + 4];   // transposed: CI=128: 16.5 KB
    int tid = threadIdx.x;
    for (int i = tid; i < CI * HID_; i += 256) {
        int c = i / HID_, o = i % HID_;
        sWt[o][c] = W[i];
    }
    size_t base = (size_t)blockIdx.x * 64;
    const float4* xsrc = (const float4*)(xin + base * CI);
    for (int i = tid; i < 64 * CI / 4; i += 256) {
        int row = i / (CI / 4), col = (i % (CI / 4)) * 4;
        *(float4*)&sx[row][col] = xsrc[i];
    }
    __syncthreads();

    int o2 = tid & 15, q = tid >> 4;     // 16 q-groups x 4 nodes
    int n0 = q * 4;
    double acc[4][2];
#pragma unroll
    for (int j = 0; j < 4; ++j) { acc[j][0] = 0.0; acc[j][1] = 0.0; }

    for (int c = 0; c < CI; c += 4) {
        float4 wa = *(const float4*)&sWt[o2][c];
        float4 wb = *(const float4*)&sWt[o2 + 16][c];
        double w0a = (double)wa.x, w1a = (double)wa.y,
               w2a = (double)wa.z, w3a = (double)wa.w;
        double w0b = (double)wb.x, w1b = (double)wb.y,
               w2b = (double)wb.z, w3b = (double)wb.w;
#pragma unroll
        for (int j = 0; j < 4; ++j) {
            float4 v = *(const float4*)&sx[n0 + j][c];
            double vx = (double)v.x, vy = (double)v.y,
                   vz = (double)v.z, vw = (double)v.w;
            acc[j][0] = fma(vx, w0a, acc[j][0]);
            acc[j][0] = fma(vy, w1a, acc[j][0]);
            acc[j][0] = fma(vz, w2a, acc[j][0]);
            acc[j][0] = fma(vw, w3a, acc[j][0]);
            acc[j][1] = fma(vx, w0b, acc[j][1]);
            acc[j][1] = fma(vy, w1b, acc[j][1]);
            acc[j][1] = fma(vz, w2b, acc[j][1]);
            acc[j][1] = fma(vw, w3b, acc[j][1]);
        }
    }
#pragma unroll
    for (int j = 0; j < 4; ++j) {
#pragma unroll
        for (int p = 0; p < 2; ++p) {
            int o = o2 + 16 * p;
            h[(((size_t)(o >> 3)) * NN_ + base + n0 + j) * SW + (o & 7)] = acc[j][p];
        }
    }
}

// ---------------- aggregation: paired edges, degree-balanced ---------------
__global__ __launch_bounds__(512) void agg_kernel(const double* __restrict__ h,
                                                  const unsigned short* __restrict__ srcl,
                                                  const int* __restrict__ gstart,
                                                  const unsigned short* __restrict__ nperm,
                                                  const double* __restrict__ disd,
                                                  const float* __restrict__ bias,
                                                  float* __restrict__ xoutf) {
    __shared__ double hd2[SW * HP];            // 32.8 KB, channel-major
    __shared__ unsigned short ssrc[EGP];       // 17.4 KB
    __shared__ unsigned short sstart[N_ + 2];  // 1 KB
    __shared__ unsigned short sperm[N_];       // 1 KB
    int g = blockIdx.x, st = blockIdx.y, tid = threadIdx.x;
    size_t nbase = (size_t)g * N_;

    for (int i = tid; i < EGP; i += 512) ssrc[i] = srcl[(size_t)g * EGP + i];
    for (int i = tid; i <= N_; i += 512) sstart[i] = (unsigned short)gstart[g * (N_ + 1) + i];
    sperm[tid] = nperm[g * N_ + tid];
    __syncthreads();

    const double* hraw = h + ((size_t)st * NN_ + nbase) * SW;
    const double* dg = disd + nbase;
    for (int i = tid; i < N_ * SW; i += 512) {
        int s = i >> 3, oc = i & 7;
        hd2[oc * HP + s] = hraw[i] * dg[s];
    }
    if (tid < SW) hd2[tid * HP + N_] = -0.0;   // sentinel
    __syncthreads();

    int oc = tid & 7, grp = tid >> 3;   // 64 node-groups x 8 channels
    const double* hrow = hd2 + oc * HP;
    const unsigned int* ssrc32 = (const unsigned int*)ssrc;
    double b = (double)bias[st * SW + oc];

    int nn[8], e0h[8], e1h[8];
    double a[8];
    int mx = 0;
#pragma unroll
    for (int j = 0; j < 8; ++j) {
        int n = sperm[grp * 8 + j];
        nn[j] = n;
        e0h[j] = sstart[n] >> 1;
        e1h[j] = sstart[n + 1] >> 1;
        a[j] = 0.0;
        int d = e1h[j] - e0h[j];
        mx = d > mx ? d : mx;
    }
    for (int t = 0; t < mx; ++t) {
#pragma unroll
        for (int j = 0; j < 8; ++j) {
            int idx = e0h[j] + t;
            if (idx < e1h[j]) {
                unsigned int pr = ssrc32[idx];
                a[j] += hrow[pr & 0xFFFFu];
                a[j] += hrow[pr >> 16];
            }
        }
    }
#pragma unroll
    for (int j = 0; j < 8; ++j) {
        int n = nn[j];
        double dn = dg[n];
        double v = a[j] * dn + hrow[n] * dn + b;
        xoutf[(nbase + n) * HID_ + st * SW + oc] = tanhf((float)v);
    }
}

// ---------------- layer 3 (32 -> 1): fp32 key = round(fp64 tanh) -----------
__global__ __launch_bounds__(512) void gcn3_kernel(const float* __restrict__ xin,
                                                   const float* __restrict__ W2,
                                                   const float* __restrict__ b2,
                                                   const unsigned short* __restrict__ srcl,
                                                   const int* __restrict__ gstart,
                                                   const double* __restrict__ disd,
                                                   float* __restrict__ x3f) {
    __shared__ double h1[N_ + 1];
    __shared__ unsigned short ssrc[EGP];
    __shared__ int sstart[N_ + 1];
    __shared__ double sdis[N_ + 1];
    int g = blockIdx.x, tid = threadIdx.x;
    size_t nbase = (size_t)g * N_;

    for (int i = tid; i < EGP; i += 512) ssrc[i] = srcl[(size_t)g * EGP + i];
    for (int i = tid; i <= N_; i += 512) sstart[i] = gstart[g * (N_ + 1) + i];
    if (tid == 0) { h1[N_] = -0.0; sdis[N_] = 1.0; }   // sentinel term: -0.0
    int n = tid;
    {
        double a = 0.0;
#pragma unroll
        for (int c = 0; c < HID_; ++c)
            a = fma((double)xin[(nbase + n) * HID_ + c], (double)W2[c], a);
        h1[n] = a;
        sdis[n] = disd[nbase + n];
    }
    __syncthreads();

    int e0 = sstart[n], e1 = sstart[n + 1];
    double a = 0.0;
    for (int e = e0; e < e1; ++e) {
        int s = ssrc[e];
        a += h1[s] * sdis[s];
    }
    double dn = sdis[n];
    double v = a * dn + h1[n] * dn * dn + (double)b2[0];
    x3f[nbase + n] = (float)tanh(v);   // fp32 rank key AND feature value
}

// ---------------- per-graph head: fp32 keys, ulp-window tie -> index -------
__global__ __launch_bounds__(256) void head_kernel(const float* __restrict__ x1,
                                                   const float* __restrict__ x2,
                                                   const float* __restrict__ x3f,
                                                   const float* __restrict__ c1w,
                                                   const float* __restrict__ c1b,
                                                   const float* __restrict__ c2w,
                                                   const float* __restrict__ c2b,
                                                   const float* __restrict__ l1w,
                                                   const float* __restrict__ l1b,
                                                   const float* __restrict__ l2w,
                                                   const float* __restrict__ l2b,
                                                   float* __restrict__ out) {
    int g = blockIdx.x;
    size_t nbase = (size_t)g * N_;
    __shared__ float sv[N_];
    __shared__ int   topk[K_];
    __shared__ float pooled[K_][LAT_];
    __shared__ float c1[16][K_];
    __shared__ float mp[16][10];
    __shared__ float c2[32 * 6];
    __shared__ float l1[128];

    for (int i = threadIdx.x; i < K_; i += 256) topk[i] = i;  // fallback
    for (int i = threadIdx.x; i < N_; i += 256) sv[i] = x3f[nbase + i];
    __syncthreads();

    // top-K descending on fp32 keys; pairs within ~1.5 ulp (relative) are
    // np-fp32 ties -> stable order (lower index first).
    for (int i = threadIdx.x; i < N_; i += 256) {
        float v = sv[i];
        int rank = 0;
        for (int j = 0; j < N_; ++j) {
            float u = sv[j];
            float mag = fmaxf(fabsf(u), fabsf(v));
            bool tie = fabsf(u - v) <= EPS_REL * mag;
            bool beats = tie ? (j < i) : (u > v);
            rank += beats;
        }
        if (rank < K_) topk[rank] = i;
    }
    __syncthreads();

    for (int i = threadIdx.x; i < K_ * LAT_; i += 256) {
        int k = i / LAT_, c = i % LAT_;
        int node = topk[k];
        float f;
        if (c < HID_)            f = x1[(nbase + node) * HID_ + c];
        else if (c < 2 * HID_)   f = x2[(nbase + node) * HID_ + (c - HID_)];
        else                     f = sv[node];
        pooled[k][c] = f;
    }
    __syncthreads();

    for (int i = threadIdx.x; i < 16 * K_; i += 256) {
        int o = i / K_, k = i % K_;
        float acc = c1b[o];
        for (int c = 0; c < LAT_; ++c) acc += pooled[k][c] * c1w[o * LAT_ + c];
        c1[o][k] = fmaxf(acc, 0.f);
    }
    __syncthreads();

    for (int i = threadIdx.x; i < 160; i += 256) {
        int o = i / 10, t = i % 10;
        mp[o][t] = fmaxf(c1[o][2 * t], c1[o][2 * t + 1]);
    }
    __syncthreads();

    for (int i = threadIdx.x; i < 192; i += 256) {
        int o = i / 6, t = i % 6;
        float acc = c2b[o];
        for (int ic = 0; ic < 16; ++ic)
#pragma unroll
            for (int j = 0; j < 5; ++j)
                acc += mp[ic][t + j] * c2w[(o * 16 + ic) * 5 + j];
        c2[o * 6 + t] = fmaxf(acc, 0.f);
    }
    __syncthreads();

    for (int i = threadIdx.x; i < 128; i += 256) {
        float acc = l1b[i];
        for (int c = 0; c < 192; ++c) acc += c2[c] * l1w[c * 128 + i];
        l1[i] = fmaxf(acc, 0.f);
    }
    __syncthreads();

    for (int i = threadIdx.x; i < 2; i += 256) {
        float acc = l2b[i];
        for (int c = 0; c < 128; ++c) acc += l1[c] * l2w[c * 2 + i];
        out[g * 2 + i] = acc;
    }
}

extern "C" void kernel_launch(void* const* d_in, const int* in_sizes, int n_in,
                              void* d_out, int out_size, void* d_ws, size_t ws_size,
                              hipStream_t stream) {
    const float* x   = (const float*)d_in[0];
    const int*   ei  = (const int*)d_in[1];
    const float* W0  = (const float*)d_in[3];
    const float* b0  = (const float*)d_in[4];
    const float* W1  = (const float*)d_in[5];
    const float* b1  = (const float*)d_in[6];
    const float* W2  = (const float*)d_in[7];
    const float* b2  = (const float*)d_in[8];
    const float* c1w = (const float*)d_in[9];
    const float* c1b = (const float*)d_in[10];
    const float* c2w = (const float*)d_in[11];
    const float* c2b = (const float*)d_in[12];
    const float* l1w = (const float*)d_in[13];
    const float* l1b = (const float*)d_in[14];
    const float* l2w = (const float*)d_in[15];
    const float* l2b = (const float*)d_in[16];

    const int* src = ei;
    const int* dst = ei + (size_t)G_ * EG_;

    char* wsb = (char*)d_ws;
    double* h64  = (double*)wsb;                 wsb += (size_t)NN_ * HID_ * 8;     // 64 MiB (stripe-major)
    unsigned short* srcl = (unsigned short*)wsb; wsb += (size_t)G_ * EGP * 2;       // 8.5 MiB
    int* gstart = (int*)wsb;                     wsb += (size_t)G_ * (N_ + 1) * 4;  // 1 MiB
    unsigned short* nperm = (unsigned short*)wsb; wsb += (size_t)G_ * N_ * 2;       // 0.5 MiB
    double* disd = (double*)wsb;                 wsb += (size_t)NN_ * 8;            // 2 MiB
    float*  x3f  = (float*)wsb;                  wsb += (size_t)NN_ * 4;            // 1 MiB
    float*  x1f  = (float*)wsb;                  wsb += (size_t)NN_ * HID_ * 4;     // 32 MiB
    float*  x2f  = (float*)wsb;                  wsb += (size_t)NN_ * HID_ * 4;     // 32 MiB

    dim3 agrid(G_, NSTRIPE);
    csr2_kernel<<<G_, 512, 0, stream>>>(src, dst, srcl, gstart, nperm, disd);
    mm_kernel<CIN_><<<NN_ / 64, 256, 0, stream>>>(x, W0, h64);
    agg_kernel<<<agrid, 512, 0, stream>>>(h64, srcl, gstart, nperm, disd, b0, x1f);
    mm_kernel<HID_><<<NN_ / 64, 256, 0, stream>>>(x1f, W1, h64);
    agg_kernel<<<agrid, 512, 0, stream>>>(h64, srcl, gstart, nperm, disd, b1, x2f);
    gcn3_kernel<<<G_, 512, 0, stream>>>(x2f, W2, b2, srcl, gstart, disd, x3f);
    head_kernel<<<G_, 256, 0, stream>>>(x1f, x2f, x3f, c1w, c1b, c2w, c2b,
                                        l1w, l1b, l2w, l2b, (float*)d_out);
}

// Round 20
// 353.048 us; speedup vs baseline: 1.6584x; 1.0501x over previous
//
#include <hip/hip_runtime.h>
#include <math.h>

#define G_ 512
#define N_ 512
#define NN_ (G_*N_)
#define EG_ 8192
#define EGP 8704      // padded edge capacity per graph (even-padded bins)
#define CIN_ 128
#define HID_ 32
#define K_ 20
#define LAT_ 65
#define NSTRIPE 4
#define SW 8          // channels per stripe
#define HP 513        // hd2 row pitch (doubles); slot 512 = sentinel -0.0

// relative tie window: ~1.5 ulp of fp32 (2^-23 = 1.19e-7)
#define EPS_REL 1.8e-7f

// ---------------- CSR build v4: histogram-balanced nperm (O(N)) ------------
// nperm needs NO stability: it only assigns nodes to threads; each node's
// sum chain is fixed by the CSR, so any bijection gives bit-identical output.
__global__ __launch_bounds__(512) void csr2_kernel(const int* __restrict__ src,
                                                   const int* __restrict__ dst,
                                                   unsigned short* __restrict__ srcl,
                                                   int* __restrict__ gstart,
                                                   unsigned short* __restrict__ nperm,
                                                   double* __restrict__ disd) {
    __shared__ int cnt[N_];
    __shared__ int startv[N_];
    __shared__ int tmpv[N_];
    __shared__ int cursor[N_];
    __shared__ int hcur[128];
    __shared__ unsigned short binE[EGP];   // 17 KB, 0xFFFF = hole
    int g = blockIdx.x, tid = threadIdx.x;
    const int* ds = dst + (size_t)g * EG_;
    const int* ss = src + (size_t)g * EG_;
    int nb = g * N_;

    cnt[tid] = 0;
    if (tid < 128) hcur[tid] = 0;
    for (int i = tid; i < EGP; i += 512) binE[i] = 0xFFFF;
    __syncthreads();
    for (int e = tid; e < EG_; e += 512) atomicAdd(&cnt[ds[e] - nb], 1);
    __syncthreads();

    // degree histogram (bins clamped at 127)
    int mydeg = cnt[tid];
    int db = mydeg < 127 ? mydeg : 127;
    atomicAdd(&hcur[db], 1);
    __syncthreads();
    if (tid == 0) {                       // exclusive prefix over 128 bins
        int run = 0;
        for (int d = 0; d < 128; ++d) { int v = hcur[d]; hcur[d] = run; run += v; }
    }
    __syncthreads();
    {
        int slot = atomicAdd(&hcur[db], 1);
        nperm[g * N_ + slot] = (unsigned short)tid;
    }

    int pc = (mydeg + 1) & ~1;            // even-padded bin size
    startv[tid] = pc;
    __syncthreads();
    for (int off = 1; off < N_; off <<= 1) {
        tmpv[tid] = startv[tid] + (tid >= off ? startv[tid - off] : 0);
        __syncthreads();
        startv[tid] = tmpv[tid];
        __syncthreads();
    }

    int excl = startv[tid] - pc;
    cursor[tid] = excl;
    gstart[g * (N_ + 1) + tid] = excl;
    if (tid == 511) gstart[g * (N_ + 1) + N_] = startv[511];
    disd[nb + tid] = 1.0 / sqrt((double)(mydeg + 1));
    __syncthreads();

    for (int e = tid; e < EG_; e += 512) {
        int d = ds[e] - nb;
        int slot = atomicAdd(&cursor[d], 1);
        binE[slot] = (unsigned short)e;
    }
    __syncthreads();

    {   // canonicalize own bin: insertion sort by edge id (original order)
        int n = mydeg;
        for (int i = 1; i < n; ++i) {
            unsigned short key = binE[excl + i];
            int j = i - 1;
            while (j >= 0 && binE[excl + j] > key) {
                binE[excl + j + 1] = binE[excl + j];
                --j;
            }
            binE[excl + j + 1] = key;
        }
    }
    __syncthreads();

    for (int i = tid; i < EGP; i += 512) {
        unsigned short e = binE[i];
        srcl[(size_t)g * EGP + i] =
            (e == 0xFFFF) ? (unsigned short)N_ : (unsigned short)(ss[e] - nb);
    }
}

// ---------------- matmul: h[n][o] = sum_c x[n][c]*W[c][o], fp64 acc --------
// 64 nodes/block, 256 threads; thread = (q -> 4 nodes, o2 -> channels 2*o2,
// 2*o2+1: same stripe -> one double2 store/node). c-ascending fma per chain
// (bit-identical). Writes h stripe-major.
template <int CI>
__global__ __launch_bounds__(256) void mm_kernel(const float* __restrict__ xin,
                                                 const float* __restrict__ W,
                                                 double* __restrict__ h) {
    __shared__ float sx[64][CI + 4];      // CI=128: 33.8 KB ; CI=32: 9.2 KB
    __shared__ float sWt[HID_][CI + 5];   // transposed, pitch 133
    int tid = threadIdx.x;
    for (int i = tid; i < CI * HID_; i += 256) {
        int c = i / HID_, o = i % HID_;
        sWt[o][c] = W[i];
    }
    size_t base = (size_t)blockIdx.x * 64;
    const float4* xsrc = (const float4*)(xin + base * CI);
    for (int i = tid; i < 64 * CI / 4; i += 256) {
        int row = i / (CI / 4), col = (i % (CI / 4)) * 4;
        *(float4*)&sx[row][col] = xsrc[i];
    }
    __syncthreads();

    int o2 = tid & 15, q = tid >> 4;     // 16 q-groups x 4 nodes
    int n0 = q * 4;
    double acc[4][2];
#pragma unroll
    for (int j = 0; j < 4; ++j) { acc[j][0] = 0.0; acc[j][1] = 0.0; }

    for (int c = 0; c < CI; c += 4) {
        float4 wa = *(const float4*)&sWt[2 * o2][c];
        float4 wb = *(const float4*)&sWt[2 * o2 + 1][c];
        double w0a = (double)wa.x, w1a = (double)wa.y,
               w2a = (double)wa.z, w3a = (double)wa.w;
        double w0b = (double)wb.x, w1b = (double)wb.y,
               w2b = (double)wb.z, w3b = (double)wb.w;
#pragma unroll
        for (int j = 0; j < 4; ++j) {
            float4 v = *(const float4*)&sx[n0 + j][c];
            double vx = (double)v.x, vy = (double)v.y,
                   vz = (double)v.z, vw = (double)v.w;
            acc[j][0] = fma(vx, w0a, acc[j][0]);
            acc[j][0] = fma(vy, w1a, acc[j][0]);
            acc[j][0] = fma(vz, w2a, acc[j][0]);
            acc[j][0] = fma(vw, w3a, acc[j][0]);
            acc[j][1] = fma(vx, w0b, acc[j][1]);
            acc[j][1] = fma(vy, w1b, acc[j][1]);
            acc[j][1] = fma(vz, w2b, acc[j][1]);
            acc[j][1] = fma(vw, w3b, acc[j][1]);
        }
    }
    int stripe = o2 >> 2;
    int oc = (o2 & 3) * 2;
#pragma unroll
    for (int j = 0; j < 4; ++j) {
        double2 val;
        val.x = acc[j][0];
        val.y = acc[j][1];
        *(double2*)&h[(((size_t)stripe) * NN_ + base + n0 + j) * SW + oc] = val;
    }
}

// ---------------- aggregation: paired edges, degree-balanced ---------------
__global__ __launch_bounds__(512) void agg_kernel(const double* __restrict__ h,
                                                  const unsigned short* __restrict__ srcl,
                                                  const int* __restrict__ gstart,
                                                  const unsigned short* __restrict__ nperm,
                                                  const double* __restrict__ disd,
                                                  const float* __restrict__ bias,
                                                  float* __restrict__ xoutf) {
    __shared__ double hd2[SW * HP];            // 32.8 KB, channel-major
    __shared__ unsigned short ssrc[EGP];       // 17.4 KB
    __shared__ unsigned short sstart[N_ + 2];  // 1 KB
    __shared__ unsigned short sperm[N_];       // 1 KB
    int g = blockIdx.x, st = blockIdx.y, tid = threadIdx.x;
    size_t nbase = (size_t)g * N_;

    for (int i = tid; i < EGP; i += 512) ssrc[i] = srcl[(size_t)g * EGP + i];
    for (int i = tid; i <= N_; i += 512) sstart[i] = (unsigned short)gstart[g * (N_ + 1) + i];
    sperm[tid] = nperm[g * N_ + tid];
    __syncthreads();

    const double* hraw = h + ((size_t)st * NN_ + nbase) * SW;
    const double* dg = disd + nbase;
    for (int i = tid; i < N_ * SW; i += 512) {
        int s = i >> 3, oc = i & 7;
        hd2[oc * HP + s] = hraw[i] * dg[s];
    }
    if (tid < SW) hd2[tid * HP + N_] = -0.0;   // sentinel
    __syncthreads();

    int oc = tid & 7, grp = tid >> 3;   // 64 node-groups x 8 channels
    const double* hrow = hd2 + oc * HP;
    const unsigned int* ssrc32 = (const unsigned int*)ssrc;
    double b = (double)bias[st * SW + oc];

    int nn[8], e0h[8], e1h[8];
    double a[8];
    int mx = 0;
#pragma unroll
    for (int j = 0; j < 8; ++j) {
        int n = sperm[grp * 8 + j];
        nn[j] = n;
        e0h[j] = sstart[n] >> 1;
        e1h[j] = sstart[n + 1] >> 1;
        a[j] = 0.0;
        int d = e1h[j] - e0h[j];
        mx = d > mx ? d : mx;
    }
    for (int t = 0; t < mx; ++t) {
#pragma unroll
        for (int j = 0; j < 8; ++j) {
            int idx = e0h[j] + t;
            if (idx < e1h[j]) {
                unsigned int pr = ssrc32[idx];
                a[j] += hrow[pr & 0xFFFFu];
                a[j] += hrow[pr >> 16];
            }
        }
    }
#pragma unroll
    for (int j = 0; j < 8; ++j) {
        int n = nn[j];
        double dn = dg[n];
        double v = a[j] * dn + hrow[n] * dn + b;
        xoutf[(nbase + n) * HID_ + st * SW + oc] = tanhf((float)v);
    }
}

// ---------------- layer 3 (32 -> 1): fp32 key = round(fp64 tanh) -----------
__global__ __launch_bounds__(512) void gcn3_kernel(const float* __restrict__ xin,
                                                   const float* __restrict__ W2,
                                                   const float* __restrict__ b2,
                                                   const unsigned short* __restrict__ srcl,
                                                   const int* __restrict__ gstart,
                                                   const double* __restrict__ disd,
                                                   float* __restrict__ x3f) {
    __shared__ double h1[N_ + 1];
    __shared__ unsigned short ssrc[EGP];
    __shared__ int sstart[N_ + 1];
    __shared__ double sdis[N_ + 1];
    int g = blockIdx.x, tid = threadIdx.x;
    size_t nbase = (size_t)g * N_;

    for (int i = tid; i < EGP; i += 512) ssrc[i] = srcl[(size_t)g * EGP + i];
    for (int i = tid; i <= N_; i += 512) sstart[i] = gstart[g * (N_ + 1) + i];
    if (tid == 0) { h1[N_] = -0.0; sdis[N_] = 1.0; }   // sentinel term: -0.0
    int n = tid;
    {
        double a = 0.0;
#pragma unroll
        for (int c = 0; c < HID_; ++c)
            a = fma((double)xin[(nbase + n) * HID_ + c], (double)W2[c], a);
        h1[n] = a;
        sdis[n] = disd[nbase + n];
    }
    __syncthreads();

    int e0 = sstart[n], e1 = sstart[n + 1];
    double a = 0.0;
    for (int e = e0; e < e1; ++e) {
        int s = ssrc[e];
        a += h1[s] * sdis[s];
    }
    double dn = sdis[n];
    double v = a * dn + h1[n] * dn * dn + (double)b2[0];
    x3f[nbase + n] = (float)tanh(v);   // fp32 rank key AND feature value
}

// ---------------- per-graph head: fp32 keys, ulp-window tie -> index -------
__global__ __launch_bounds__(256) void head_kernel(const float* __restrict__ x1,
                                                   const float* __restrict__ x2,
                                                   const float* __restrict__ x3f,
                                                   const float* __restrict__ c1w,
                                                   const float* __restrict__ c1b,
                                                   const float* __restrict__ c2w,
                                                   const float* __restrict__ c2b,
                                                   const float* __restrict__ l1w,
                                                   const float* __restrict__ l1b,
                                                   const float* __restrict__ l2w,
                                                   const float* __restrict__ l2b,
                                                   float* __restrict__ out) {
    int g = blockIdx.x;
    size_t nbase = (size_t)g * N_;
    __shared__ float sv[N_];
    __shared__ int   topk[K_];
    __shared__ float pooled[K_][LAT_];
    __shared__ float c1[16][K_];
    __shared__ float mp[16][10];
    __shared__ float c2[32 * 6];
    __shared__ float l1[128];

    for (int i = threadIdx.x; i < K_; i += 256) topk[i] = i;  // fallback
    for (int i = threadIdx.x; i < N_; i += 256) sv[i] = x3f[nbase + i];
    __syncthreads();

    // top-K descending on fp32 keys; pairs within ~1.5 ulp (relative) are
    // np-fp32 ties -> stable order (lower index first).
    for (int i = threadIdx.x; i < N_; i += 256) {
        float v = sv[i];
        int rank = 0;
        for (int j = 0; j < N_; ++j) {
            float u = sv[j];
            float mag = fmaxf(fabsf(u), fabsf(v));
            bool tie = fabsf(u - v) <= EPS_REL * mag;
            bool beats = tie ? (j < i) : (u > v);
            rank += beats;
        }
        if (rank < K_) topk[rank] = i;
    }
    __syncthreads();

    for (int i = threadIdx.x; i < K_ * LAT_; i += 256) {
        int k = i / LAT_, c = i % LAT_;
        int node = topk[k];
        float f;
        if (c < HID_)            f = x1[(nbase + node) * HID_ + c];
        else if (c < 2 * HID_)   f = x2[(nbase + node) * HID_ + (c - HID_)];
        else                     f = sv[node];
        pooled[k][c] = f;
    }
    __syncthreads();

    for (int i = threadIdx.x; i < 16 * K_; i += 256) {
        int o = i / K_, k = i % K_;
        float acc = c1b[o];
        for (int c = 0; c < LAT_; ++c) acc += pooled[k][c] * c1w[o * LAT_ + c];
        c1[o][k] = fmaxf(acc, 0.f);
    }
    __syncthreads();

    for (int i = threadIdx.x; i < 160; i += 256) {
        int o = i / 10, t = i % 10;
        mp[o][t] = fmaxf(c1[o][2 * t], c1[o][2 * t + 1]);
    }
    __syncthreads();

    for (int i = threadIdx.x; i < 192; i += 256) {
        int o = i / 6, t = i % 6;
        float acc = c2b[o];
        for (int ic = 0; ic < 16; ++ic)
#pragma unroll
            for (int j = 0; j < 5; ++j)
                acc += mp[ic][t + j] * c2w[(o * 16 + ic) * 5 + j];
        c2[o * 6 + t] = fmaxf(acc, 0.f);
    }
    __syncthreads();

    for (int i = threadIdx.x; i < 128; i += 256) {
        float acc = l1b[i];
        for (int c = 0; c < 192; ++c) acc += c2[c] * l1w[c * 128 + i];
        l1[i] = fmaxf(acc, 0.f);
    }
    __syncthreads();

    for (int i = threadIdx.x; i < 2; i += 256) {
        float acc = l2b[i];
        for (int c = 0; c < 128; ++c) acc += l1[c] * l2w[c * 2 + i];
        out[g * 2 + i] = acc;
    }
}

extern "C" void kernel_launch(void* const* d_in, const int* in_sizes, int n_in,
                              void* d_out, int out_size, void* d_ws, size_t ws_size,
                              hipStream_t stream) {
    const float* x   = (const float*)d_in[0];
    const int*   ei  = (const int*)d_in[1];
    const float* W0  = (const float*)d_in[3];
    const float* b0  = (const float*)d_in[4];
    const float* W1  = (const float*)d_in[5];
    const float* b1  = (const float*)d_in[6];
    const float* W2  = (const float*)d_in[7];
    const float* b2  = (const float*)d_in[8];
    const float* c1w = (const float*)d_in[9];
    const float* c1b = (const float*)d_in[10];
    const float* c2w = (const float*)d_in[11];
    const float* c2b = (const float*)d_in[12];
    const float* l1w = (const float*)d_in[13];
    const float* l1b = (const float*)d_in[14];
    const float* l2w = (const float*)d_in[15];
    const float* l2b = (const float*)d_in[16];

    const int* src = ei;
    const int* dst = ei + (size_t)G_ * EG_;

    char* wsb = (char*)d_ws;
    double* h64  = (double*)wsb;                 wsb += (size_t)NN_ * HID_ * 8;     // 64 MiB (stripe-major)
    unsigned short* srcl = (unsigned short*)wsb; wsb += (size_t)G_ * EGP * 2;       // 8.5 MiB
    int* gstart = (int*)wsb;                     wsb += (size_t)G_ * (N_ + 1) * 4;  // 1 MiB
    unsigned short* nperm = (unsigned short*)wsb; wsb += (size_t)G_ * N_ * 2;       // 0.5 MiB
    double* disd = (double*)wsb;                 wsb += (size_t)NN_ * 8;            // 2 MiB
    float*  x3f  = (float*)wsb;                  wsb += (size_t)NN_ * 4;            // 1 MiB
    float*  x1f  = (float*)wsb;                  wsb += (size_t)NN_ * HID_ * 4;     // 32 MiB
    float*  x2f  = (float*)wsb;                  wsb += (size_t)NN_ * HID_ * 4;     // 32 MiB

    dim3 agrid(G_, NSTRIPE);
    csr2_kernel<<<G_, 512, 0, stream>>>(src, dst, srcl, gstart, nperm, disd);
    mm_kernel<CIN_><<<NN_ / 64, 256, 0, stream>>>(x, W0, h64);
    agg_kernel<<<agrid, 512, 0, stream>>>(h64, srcl, gstart, nperm, disd, b0, x1f);
    mm_kernel<HID_><<<NN_ / 64, 256, 0, stream>>>(x1f, W1, h64);
    agg_kernel<<<agrid, 512, 0, stream>>>(h64, srcl, gstart, nperm, disd, b1, x2f);
    gcn3_kernel<<<G_, 512, 0, stream>>>(x2f, W2, b2, srcl, gstart, disd, x3f);
    head_kernel<<<G_, 256, 0, stream>>>(x1f, x2f, x3f, c1w, c1b, c2w, c2b,
                                        l1w, l1b, l2w, l2b, (float*)d_out);
}

// Round 21
// 344.436 us; speedup vs baseline: 1.6999x; 1.0250x over previous
//
#include <hip/hip_runtime.h>
#include <math.h>

#define G_ 512
#define N_ 512
#define NN_ (G_*N_)
#define EG_ 8192
#define EGP 8704      // padded edge capacity per graph (even-padded bins)
#define CIN_ 128
#define HID_ 32
#define K_ 20
#define LAT_ 65
#define NSTRIPE 4
#define SW 8          // channels per stripe
#define HP 513        // hd2 row pitch (doubles); slot 512 = sentinel -0.0

// relative tie window: ~1.5 ulp of fp32 (2^-23 = 1.19e-7)
#define EPS_REL 1.8e-7f

// ---------------- CSR build v4: histogram-balanced nperm (O(N)) ------------
__global__ __launch_bounds__(512) void csr2_kernel(const int* __restrict__ src,
                                                   const int* __restrict__ dst,
                                                   unsigned short* __restrict__ srcl,
                                                   int* __restrict__ gstart,
                                                   unsigned short* __restrict__ nperm,
                                                   double* __restrict__ disd) {
    __shared__ int cnt[N_];
    __shared__ int startv[N_];
    __shared__ int tmpv[N_];
    __shared__ int cursor[N_];
    __shared__ int hcur[128];
    __shared__ unsigned short binE[EGP];   // 17 KB, 0xFFFF = hole
    int g = blockIdx.x, tid = threadIdx.x;
    const int* ds = dst + (size_t)g * EG_;
    const int* ss = src + (size_t)g * EG_;
    int nb = g * N_;

    cnt[tid] = 0;
    if (tid < 128) hcur[tid] = 0;
    for (int i = tid; i < EGP; i += 512) binE[i] = 0xFFFF;
    __syncthreads();
    for (int e = tid; e < EG_; e += 512) atomicAdd(&cnt[ds[e] - nb], 1);
    __syncthreads();

    int mydeg = cnt[tid];
    int db = mydeg < 127 ? mydeg : 127;
    atomicAdd(&hcur[db], 1);
    __syncthreads();
    if (tid == 0) {
        int run = 0;
        for (int d = 0; d < 128; ++d) { int v = hcur[d]; hcur[d] = run; run += v; }
    }
    __syncthreads();
    {
        int slot = atomicAdd(&hcur[db], 1);
        nperm[g * N_ + slot] = (unsigned short)tid;
    }

    int pc = (mydeg + 1) & ~1;            // even-padded bin size
    startv[tid] = pc;
    __syncthreads();
    for (int off = 1; off < N_; off <<= 1) {
        tmpv[tid] = startv[tid] + (tid >= off ? startv[tid - off] : 0);
        __syncthreads();
        startv[tid] = tmpv[tid];
        __syncthreads();
    }

    int excl = startv[tid] - pc;
    cursor[tid] = excl;
    gstart[g * (N_ + 1) + tid] = excl;
    if (tid == 511) gstart[g * (N_ + 1) + N_] = startv[511];
    disd[nb + tid] = 1.0 / sqrt((double)(mydeg + 1));
    __syncthreads();

    for (int e = tid; e < EG_; e += 512) {
        int d = ds[e] - nb;
        int slot = atomicAdd(&cursor[d], 1);
        binE[slot] = (unsigned short)e;
    }
    __syncthreads();

    {   // canonicalize own bin: insertion sort by edge id (original order)
        int n = mydeg;
        for (int i = 1; i < n; ++i) {
            unsigned short key = binE[excl + i];
            int j = i - 1;
            while (j >= 0 && binE[excl + j] > key) {
                binE[excl + j + 1] = binE[excl + j];
                --j;
            }
            binE[excl + j + 1] = key;
        }
    }
    __syncthreads();

    for (int i = tid; i < EGP; i += 512) {
        unsigned short e = binE[i];
        srcl[(size_t)g * EGP + i] =
            (e == 0xFFFF) ? (unsigned short)N_ : (unsigned short)(ss[e] - nb);
    }
}

// ---------------- matmul: h[n][o] = sum_c x[n][c]*W[c][o], fp64 acc --------
template <int CI>
__global__ __launch_bounds__(256) void mm_kernel(const float* __restrict__ xin,
                                                 const float* __restrict__ W,
                                                 double* __restrict__ h) {
    __shared__ float sx[64][CI + 4];      // CI=128: 33.8 KB ; CI=32: 9.2 KB
    __shared__ float sWt[HID_][CI + 5];   // transposed, pitch 133
    int tid = threadIdx.x;
    for (int i = tid; i < CI * HID_; i += 256) {
        int c = i / HID_, o = i % HID_;
        sWt[o][c] = W[i];
    }
    size_t base = (size_t)blockIdx.x * 64;
    const float4* xsrc = (const float4*)(xin + base * CI);
    for (int i = tid; i < 64 * CI / 4; i += 256) {
        int row = i / (CI / 4), col = (i % (CI / 4)) * 4;
        *(float4*)&sx[row][col] = xsrc[i];
    }
    __syncthreads();

    int o2 = tid & 15, q = tid >> 4;     // 16 q-groups x 4 nodes
    int n0 = q * 4;
    double acc[4][2];
#pragma unroll
    for (int j = 0; j < 4; ++j) { acc[j][0] = 0.0; acc[j][1] = 0.0; }

    for (int c = 0; c < CI; c += 4) {
        float4 wa = *(const float4*)&sWt[2 * o2][c];
        float4 wb = *(const float4*)&sWt[2 * o2 + 1][c];
        double w0a = (double)wa.x, w1a = (double)wa.y,
               w2a = (double)wa.z, w3a = (double)wa.w;
        double w0b = (double)wb.x, w1b = (double)wb.y,
               w2b = (double)wb.z, w3b = (double)wb.w;
#pragma unroll
        for (int j = 0; j < 4; ++j) {
            float4 v = *(const float4*)&sx[n0 + j][c];
            double vx = (double)v.x, vy = (double)v.y,
                   vz = (double)v.z, vw = (double)v.w;
            acc[j][0] = fma(vx, w0a, acc[j][0]);
            acc[j][0] = fma(vy, w1a, acc[j][0]);
            acc[j][0] = fma(vz, w2a, acc[j][0]);
            acc[j][0] = fma(vw, w3a, acc[j][0]);
            acc[j][1] = fma(vx, w0b, acc[j][1]);
            acc[j][1] = fma(vy, w1b, acc[j][1]);
            acc[j][1] = fma(vz, w2b, acc[j][1]);
            acc[j][1] = fma(vw, w3b, acc[j][1]);
        }
    }
    int stripe = o2 >> 2;
    int oc = (o2 & 3) * 2;
#pragma unroll
    for (int j = 0; j < 4; ++j) {
        double2 val;
        val.x = acc[j][0];
        val.y = acc[j][1];
        *(double2*)&h[(((size_t)stripe) * NN_ + base + n0 + j) * SW + oc] = val;
    }
}

// ---------------- aggregation: paired edges, degree-balanced ---------------
__global__ __launch_bounds__(512) void agg_kernel(const double* __restrict__ h,
                                                  const unsigned short* __restrict__ srcl,
                                                  const int* __restrict__ gstart,
                                                  const unsigned short* __restrict__ nperm,
                                                  const double* __restrict__ disd,
                                                  const float* __restrict__ bias,
                                                  float* __restrict__ xoutf) {
    __shared__ double hd2[SW * HP];            // 32.8 KB, channel-major
    __shared__ unsigned short ssrc[EGP];       // 17.4 KB
    __shared__ unsigned short sstart[N_ + 2];  // 1 KB
    __shared__ unsigned short sperm[N_];       // 1 KB
    int g = blockIdx.x, st = blockIdx.y, tid = threadIdx.x;
    size_t nbase = (size_t)g * N_;

    for (int i = tid; i < EGP; i += 512) ssrc[i] = srcl[(size_t)g * EGP + i];
    for (int i = tid; i <= N_; i += 512) sstart[i] = (unsigned short)gstart[g * (N_ + 1) + i];
    sperm[tid] = nperm[g * N_ + tid];
    __syncthreads();

    const double* hraw = h + ((size_t)st * NN_ + nbase) * SW;
    const double* dg = disd + nbase;
    for (int i = tid; i < N_ * SW; i += 512) {
        int s = i >> 3, oc = i & 7;
        hd2[oc * HP + s] = hraw[i] * dg[s];
    }
    if (tid < SW) hd2[tid * HP + N_] = -0.0;   // sentinel
    __syncthreads();

    int oc = tid & 7, grp = tid >> 3;   // 64 node-groups x 8 channels
    const double* hrow = hd2 + oc * HP;
    const unsigned int* ssrc32 = (const unsigned int*)ssrc;
    double b = (double)bias[st * SW + oc];

    int nn[8], e0h[8], e1h[8];
    double a[8];
    int mx = 0;
#pragma unroll
    for (int j = 0; j < 8; ++j) {
        int n = sperm[grp * 8 + j];
        nn[j] = n;
        e0h[j] = sstart[n] >> 1;
        e1h[j] = sstart[n + 1] >> 1;
        a[j] = 0.0;
        int d = e1h[j] - e0h[j];
        mx = d > mx ? d : mx;
    }
    for (int t = 0; t < mx; ++t) {
#pragma unroll
        for (int j = 0; j < 8; ++j) {
            int idx = e0h[j] + t;
            if (idx < e1h[j]) {
                unsigned int pr = ssrc32[idx];
                a[j] += hrow[pr & 0xFFFFu];
                a[j] += hrow[pr >> 16];
            }
        }
    }
#pragma unroll
    for (int j = 0; j < 8; ++j) {
        int n = nn[j];
        double dn = dg[n];
        double v = a[j] * dn + hrow[n] * dn + b;
        xoutf[(nbase + n) * HID_ + st * SW + oc] = tanhf((float)v);
    }
}

// ---------------- fused layer-3 + head (one block per graph, 512 thr) ------
// gcn3 part: bit-identical chain (c-ascending fp64 fma; padded CSR with
// sentinel). Writes sv[n] = fp32(tanh(v)) to LDS only; head part consumes it
// in the same block (no x3f global round-trip; rank scan = broadcast reads).
__global__ __launch_bounds__(512) void gcn3_head_kernel(
        const float* __restrict__ xin,      // x2f
        const float* __restrict__ W2,
        const float* __restrict__ b2,
        const unsigned short* __restrict__ srcl,
        const int* __restrict__ gstart,
        const double* __restrict__ disd,
        const float* __restrict__ x1,
        const float* __restrict__ x2,
        const float* __restrict__ c1w, const float* __restrict__ c1b,
        const float* __restrict__ c2w, const float* __restrict__ c2b,
        const float* __restrict__ l1w, const float* __restrict__ l1b,
        const float* __restrict__ l2w, const float* __restrict__ l2b,
        float* __restrict__ out) {
    __shared__ double h1[N_ + 1];
    __shared__ unsigned short ssrc[EGP];
    __shared__ int sstart[N_ + 1];
    __shared__ double sdis[N_ + 1];
    __shared__ float sv[N_];
    __shared__ int   topk[K_];
    __shared__ float pooled[K_][LAT_];
    __shared__ float c1[16][K_];
    __shared__ float mp[16][10];
    __shared__ float c2s[32 * 6];
    __shared__ float l1s[128];
    int g = blockIdx.x, tid = threadIdx.x;
    size_t nbase = (size_t)g * N_;

    // ---- gcn3: h1 = x2f @ W2 (fp64, c-ascending), then edge sum ----
    for (int i = tid; i < EGP; i += 512) ssrc[i] = srcl[(size_t)g * EGP + i];
    for (int i = tid; i <= N_; i += 512) sstart[i] = gstart[g * (N_ + 1) + i];
    if (tid == 0) { h1[N_] = -0.0; sdis[N_] = 1.0; }   // sentinel term: -0.0
    if (tid < K_) topk[tid] = tid;                      // fallback init
    int n = tid;
    {
        double a = 0.0;
#pragma unroll
        for (int c = 0; c < HID_; ++c)
            a = fma((double)xin[(nbase + n) * HID_ + c], (double)W2[c], a);
        h1[n] = a;
        sdis[n] = disd[nbase + n];
    }
    __syncthreads();

    {
        int e0 = sstart[n], e1 = sstart[n + 1];
        double a = 0.0;
        for (int e = e0; e < e1; ++e) {
            int s = ssrc[e];
            a += h1[s] * sdis[s];
        }
        double dn = sdis[n];
        double v = a * dn + h1[n] * dn * dn + (double)b2[0];
        sv[n] = (float)tanh(v);   // fp32 rank key AND feature value
    }
    __syncthreads();

    // ---- head: rank (1 node/thread, broadcast LDS reads) ----
    {
        float v = sv[n];
        int rank = 0;
        for (int j = 0; j < N_; ++j) {
            float u = sv[j];
            float mag = fmaxf(fabsf(u), fabsf(v));
            bool tie = fabsf(u - v) <= EPS_REL * mag;
            bool beats = tie ? (j < n) : (u > v);
            rank += beats;
        }
        if (rank < K_) topk[rank] = n;
    }
    __syncthreads();

    for (int i = tid; i < K_ * LAT_; i += 512) {
        int k = i / LAT_, c = i % LAT_;
        int node = topk[k];
        float f;
        if (c < HID_)            f = x1[(nbase + node) * HID_ + c];
        else if (c < 2 * HID_)   f = x2[(nbase + node) * HID_ + (c - HID_)];
        else                     f = sv[node];
        pooled[k][c] = f;
    }
    __syncthreads();

    for (int i = tid; i < 16 * K_; i += 512) {
        int o = i / K_, k = i % K_;
        float acc = c1b[o];
        for (int c = 0; c < LAT_; ++c) acc += pooled[k][c] * c1w[o * LAT_ + c];
        c1[o][k] = fmaxf(acc, 0.f);
    }
    __syncthreads();

    for (int i = tid; i < 160; i += 512) {
        int o = i / 10, t = i % 10;
        mp[o][t] = fmaxf(c1[o][2 * t], c1[o][2 * t + 1]);
    }
    __syncthreads();

    for (int i = tid; i < 192; i += 512) {
        int o = i / 6, t = i % 6;
        float acc = c2b[o];
        for (int ic = 0; ic < 16; ++ic)
#pragma unroll
            for (int j = 0; j < 5; ++j)
                acc += mp[ic][t + j] * c2w[(o * 16 + ic) * 5 + j];
        c2s[o * 6 + t] = fmaxf(acc, 0.f);
    }
    __syncthreads();

    for (int i = tid; i < 128; i += 512) {
        float acc = l1b[i];
        for (int c = 0; c < 192; ++c) acc += c2s[c] * l1w[c * 128 + i];
        l1s[i] = fmaxf(acc, 0.f);
    }
    __syncthreads();

    for (int i = tid; i < 2; i += 512) {
        float acc = l2b[i];
        for (int c = 0; c < 128; ++c) acc += l1s[c] * l2w[c * 2 + i];
        out[g * 2 + i] = acc;
    }
}

extern "C" void kernel_launch(void* const* d_in, const int* in_sizes, int n_in,
                              void* d_out, int out_size, void* d_ws, size_t ws_size,
                              hipStream_t stream) {
    const float* x   = (const float*)d_in[0];
    const int*   ei  = (const int*)d_in[1];
    const float* W0  = (const float*)d_in[3];
    const float* b0  = (const float*)d_in[4];
    const float* W1  = (const float*)d_in[5];
    const float* b1  = (const float*)d_in[6];
    const float* W2  = (const float*)d_in[7];
    const float* b2  = (const float*)d_in[8];
    const float* c1w = (const float*)d_in[9];
    const float* c1b = (const float*)d_in[10];
    const float* c2w = (const float*)d_in[11];
    const float* c2b = (const float*)d_in[12];
    const float* l1w = (const float*)d_in[13];
    const float* l1b = (const float*)d_in[14];
    const float* l2w = (const float*)d_in[15];
    const float* l2b = (const float*)d_in[16];

    const int* src = ei;
    const int* dst = ei + (size_t)G_ * EG_;

    char* wsb = (char*)d_ws;
    double* h64  = (double*)wsb;                 wsb += (size_t)NN_ * HID_ * 8;     // 64 MiB (stripe-major)
    unsigned short* srcl = (unsigned short*)wsb; wsb += (size_t)G_ * EGP * 2;       // 8.5 MiB
    int* gstart = (int*)wsb;                     wsb += (size_t)G_ * (N_ + 1) * 4;  // 1 MiB
    unsigned short* nperm = (unsigned short*)wsb; wsb += (size_t)G_ * N_ * 2;       // 0.5 MiB
    double* disd = (double*)wsb;                 wsb += (size_t)NN_ * 8;            // 2 MiB
    float*  x1f  = (float*)wsb;                  wsb += (size_t)NN_ * HID_ * 4;     // 32 MiB
    float*  x2f  = (float*)wsb;                  wsb += (size_t)NN_ * HID_ * 4;     // 32 MiB

    dim3 agrid(G_, NSTRIPE);
    csr2_kernel<<<G_, 512, 0, stream>>>(src, dst, srcl, gstart, nperm, disd);
    mm_kernel<CIN_><<<NN_ / 64, 256, 0, stream>>>(x, W0, h64);
    agg_kernel<<<agrid, 512, 0, stream>>>(h64, srcl, gstart, nperm, disd, b0, x1f);
    mm_kernel<HID_><<<NN_ / 64, 256, 0, stream>>>(x1f, W1, h64);
    agg_kernel<<<agrid, 512, 0, stream>>>(h64, srcl, gstart, nperm, disd, b1, x2f);
    gcn3_head_kernel<<<G_, 512, 0, stream>>>(x2f, W2, b2, srcl, gstart, disd,
                                             x1f, x2f, c1w, c1b, c2w, c2b,
                                             l1w, l1b, l2w, l2b, (float*)d_out);
}

// Round 22
// 335.307 us; speedup vs baseline: 1.7462x; 1.0272x over previous
//
#include <hip/hip_runtime.h>
#include <math.h>

#define G_ 512
#define N_ 512
#define NN_ (G_*N_)
#define EG_ 8192
#define EGP 8704      // padded edge capacity per graph (even-padded bins)
#define CIN_ 128
#define HID_ 32
#define K_ 20
#define LAT_ 65
#define NSTRIPE 4
#define SW 8          // channels per stripe
#define HP 513        // hd2 row pitch (doubles); slot 512 = sentinel -0.0

// relative tie window: ~1.5 ulp of fp32 (2^-23 = 1.19e-7)
#define EPS_REL 1.8e-7f

// ---------------- CSR build v4: histogram-balanced nperm (O(N)) ------------
__global__ __launch_bounds__(512) void csr2_kernel(const int* __restrict__ src,
                                                   const int* __restrict__ dst,
                                                   unsigned short* __restrict__ srcl,
                                                   int* __restrict__ gstart,
                                                   unsigned short* __restrict__ nperm,
                                                   double* __restrict__ disd) {
    __shared__ int cnt[N_];
    __shared__ int startv[N_];
    __shared__ int tmpv[N_];
    __shared__ int cursor[N_];
    __shared__ int hcur[128];
    __shared__ unsigned short binE[EGP];   // 17 KB, 0xFFFF = hole
    int g = blockIdx.x, tid = threadIdx.x;
    const int* ds = dst + (size_t)g * EG_;
    const int* ss = src + (size_t)g * EG_;
    int nb = g * N_;

    cnt[tid] = 0;
    if (tid < 128) hcur[tid] = 0;
    for (int i = tid; i < EGP; i += 512) binE[i] = 0xFFFF;
    __syncthreads();
    for (int e = tid; e < EG_; e += 512) atomicAdd(&cnt[ds[e] - nb], 1);
    __syncthreads();

    int mydeg = cnt[tid];
    int db = mydeg < 127 ? mydeg : 127;
    atomicAdd(&hcur[db], 1);
    __syncthreads();
    if (tid == 0) {
        int run = 0;
        for (int d = 0; d < 128; ++d) { int v = hcur[d]; hcur[d] = run; run += v; }
    }
    __syncthreads();
    {
        int slot = atomicAdd(&hcur[db], 1);
        nperm[g * N_ + slot] = (unsigned short)tid;
    }

    int pc = (mydeg + 1) & ~1;            // even-padded bin size
    startv[tid] = pc;
    __syncthreads();
    for (int off = 1; off < N_; off <<= 1) {
        tmpv[tid] = startv[tid] + (tid >= off ? startv[tid - off] : 0);
        __syncthreads();
        startv[tid] = tmpv[tid];
        __syncthreads();
    }

    int excl = startv[tid] - pc;
    cursor[tid] = excl;
    gstart[g * (N_ + 1) + tid] = excl;
    if (tid == 511) gstart[g * (N_ + 1) + N_] = startv[511];
    disd[nb + tid] = 1.0 / sqrt((double)(mydeg + 1));
    __syncthreads();

    for (int e = tid; e < EG_; e += 512) {
        int d = ds[e] - nb;
        int slot = atomicAdd(&cursor[d], 1);
        binE[slot] = (unsigned short)e;
    }
    __syncthreads();

    {   // canonicalize own bin: insertion sort by edge id (original order)
        int n = mydeg;
        for (int i = 1; i < n; ++i) {
            unsigned short key = binE[excl + i];
            int j = i - 1;
            while (j >= 0 && binE[excl + j] > key) {
                binE[excl + j + 1] = binE[excl + j];
                --j;
            }
            binE[excl + j + 1] = key;
        }
    }
    __syncthreads();

    for (int i = tid; i < EGP; i += 512) {
        unsigned short e = binE[i];
        srcl[(size_t)g * EGP + i] =
            (e == 0xFFFF) ? (unsigned short)N_ : (unsigned short)(ss[e] - nb);
    }
}

// ---------------- matmul (layer 1): h = x @ W0, fp64 acc -------------------
template <int CI>
__global__ __launch_bounds__(256) void mm_kernel(const float* __restrict__ xin,
                                                 const float* __restrict__ W,
                                                 double* __restrict__ h) {
    __shared__ float sx[64][CI + 4];      // CI=128: 33.8 KB
    __shared__ float sWt[HID_][CI + 5];   // transposed, pitch 133
    int tid = threadIdx.x;
    for (int i = tid; i < CI * HID_; i += 256) {
        int c = i / HID_, o = i % HID_;
        sWt[o][c] = W[i];
    }
    size_t base = (size_t)blockIdx.x * 64;
    const float4* xsrc = (const float4*)(xin + base * CI);
    for (int i = tid; i < 64 * CI / 4; i += 256) {
        int row = i / (CI / 4), col = (i % (CI / 4)) * 4;
        *(float4*)&sx[row][col] = xsrc[i];
    }
    __syncthreads();

    int o2 = tid & 15, q = tid >> 4;     // 16 q-groups x 4 nodes
    int n0 = q * 4;
    double acc[4][2];
#pragma unroll
    for (int j = 0; j < 4; ++j) { acc[j][0] = 0.0; acc[j][1] = 0.0; }

    for (int c = 0; c < CI; c += 4) {
        float4 wa = *(const float4*)&sWt[2 * o2][c];
        float4 wb = *(const float4*)&sWt[2 * o2 + 1][c];
        double w0a = (double)wa.x, w1a = (double)wa.y,
               w2a = (double)wa.z, w3a = (double)wa.w;
        double w0b = (double)wb.x, w1b = (double)wb.y,
               w2b = (double)wb.z, w3b = (double)wb.w;
#pragma unroll
        for (int j = 0; j < 4; ++j) {
            float4 v = *(const float4*)&sx[n0 + j][c];
            double vx = (double)v.x, vy = (double)v.y,
                   vz = (double)v.z, vw = (double)v.w;
            acc[j][0] = fma(vx, w0a, acc[j][0]);
            acc[j][0] = fma(vy, w1a, acc[j][0]);
            acc[j][0] = fma(vz, w2a, acc[j][0]);
            acc[j][0] = fma(vw, w3a, acc[j][0]);
            acc[j][1] = fma(vx, w0b, acc[j][1]);
            acc[j][1] = fma(vy, w1b, acc[j][1]);
            acc[j][1] = fma(vz, w2b, acc[j][1]);
            acc[j][1] = fma(vw, w3b, acc[j][1]);
        }
    }
    int stripe = o2 >> 2;
    int oc = (o2 & 3) * 2;
#pragma unroll
    for (int j = 0; j < 4; ++j) {
        double2 val;
        val.x = acc[j][0];
        val.y = acc[j][1];
        *(double2*)&h[(((size_t)stripe) * NN_ + base + n0 + j) * SW + oc] = val;
    }
}

// ---------------- aggregation (layer 1): reads h64, paired edges -----------
__global__ __launch_bounds__(512) void agg_kernel(const double* __restrict__ h,
                                                  const unsigned short* __restrict__ srcl,
                                                  const int* __restrict__ gstart,
                                                  const unsigned short* __restrict__ nperm,
                                                  const double* __restrict__ disd,
                                                  const float* __restrict__ bias,
                                                  float* __restrict__ xoutf) {
    __shared__ double hd2[SW * HP];            // 32.8 KB, channel-major
    __shared__ unsigned short ssrc[EGP];       // 17.4 KB
    __shared__ unsigned short sstart[N_ + 2];  // 1 KB
    __shared__ unsigned short sperm[N_];       // 1 KB
    int g = blockIdx.x, st = blockIdx.y, tid = threadIdx.x;
    size_t nbase = (size_t)g * N_;

    for (int i = tid; i < EGP; i += 512) ssrc[i] = srcl[(size_t)g * EGP + i];
    for (int i = tid; i <= N_; i += 512) sstart[i] = (unsigned short)gstart[g * (N_ + 1) + i];
    sperm[tid] = nperm[g * N_ + tid];
    __syncthreads();

    const double* hraw = h + ((size_t)st * NN_ + nbase) * SW;
    const double* dg = disd + nbase;
    for (int i = tid; i < N_ * SW; i += 512) {
        int s = i >> 3, oc = i & 7;
        hd2[oc * HP + s] = hraw[i] * dg[s];
    }
    if (tid < SW) hd2[tid * HP + N_] = -0.0;   // sentinel
    __syncthreads();

    int oc = tid & 7, grp = tid >> 3;   // 64 node-groups x 8 channels
    const double* hrow = hd2 + oc * HP;
    const unsigned int* ssrc32 = (const unsigned int*)ssrc;
    double b = (double)bias[st * SW + oc];

    int nn[8], e0h[8], e1h[8];
    double a[8];
    int mx = 0;
#pragma unroll
    for (int j = 0; j < 8; ++j) {
        int n = sperm[grp * 8 + j];
        nn[j] = n;
        e0h[j] = sstart[n] >> 1;
        e1h[j] = sstart[n + 1] >> 1;
        a[j] = 0.0;
        int d = e1h[j] - e0h[j];
        mx = d > mx ? d : mx;
    }
    for (int t = 0; t < mx; ++t) {
#pragma unroll
        for (int j = 0; j < 8; ++j) {
            int idx = e0h[j] + t;
            if (idx < e1h[j]) {
                unsigned int pr = ssrc32[idx];
                a[j] += hrow[pr & 0xFFFFu];
                a[j] += hrow[pr >> 16];
            }
        }
    }
#pragma unroll
    for (int j = 0; j < 8; ++j) {
        int n = nn[j];
        double dn = dg[n];
        double v = a[j] * dn + hrow[n] * dn + b;
        xoutf[(nbase + n) * HID_ + st * SW + oc] = tanhf((float)v);
    }
}

// ---------------- fused layer-2: in-block mm (x1f@W1 slice) + aggregation --
// Thread t owns node s=t: a[oc] = sum_c fma((double)x1f[s][c],(double)W1[c][oc])
// with c ascending (IDENTICAL chain to mm_kernel), then hd2[oc][s]=a[oc]*dis.
// Removes the mm<32> dispatch + 128 MB of h64 traffic. Edge phase unchanged.
__global__ __launch_bounds__(512) void agg_mm_kernel(
        const float* __restrict__ xin,    // x1f
        const float* __restrict__ W,      // W1 [32][32]
        const unsigned short* __restrict__ srcl,
        const int* __restrict__ gstart,
        const unsigned short* __restrict__ nperm,
        const double* __restrict__ disd,
        const float* __restrict__ bias,
        float* __restrict__ xoutf) {
    __shared__ double hd2[SW * HP];            // 32.8 KB
    __shared__ unsigned short ssrc[EGP];       // 17.4 KB
    __shared__ unsigned short sstart[N_ + 2];  // 1 KB
    __shared__ unsigned short sperm[N_];       // 1 KB
    __shared__ float sW[HID_ * SW];            // W column slice, 1 KB
    int g = blockIdx.x, st = blockIdx.y, tid = threadIdx.x;
    size_t nbase = (size_t)g * N_;

    for (int i = tid; i < EGP; i += 512) ssrc[i] = srcl[(size_t)g * EGP + i];
    for (int i = tid; i <= N_; i += 512) sstart[i] = (unsigned short)gstart[g * (N_ + 1) + i];
    sperm[tid] = nperm[g * N_ + tid];
    if (tid < HID_ * SW) {
        int c = tid >> 3, oc = tid & 7;
        sW[tid] = W[c * HID_ + st * SW + oc];
    }
    __syncthreads();

    const double* dg = disd + nbase;
    {   // in-block mm: node s = tid
        int s = tid;
        const float4* xr4 = (const float4*)(xin + (nbase + s) * HID_);
        float xrow[HID_];
#pragma unroll
        for (int q = 0; q < HID_ / 4; ++q) {
            float4 v = xr4[q];
            xrow[q * 4 + 0] = v.x;
            xrow[q * 4 + 1] = v.y;
            xrow[q * 4 + 2] = v.z;
            xrow[q * 4 + 3] = v.w;
        }
        double a[SW];
#pragma unroll
        for (int oc = 0; oc < SW; ++oc) a[oc] = 0.0;
#pragma unroll
        for (int c = 0; c < HID_; ++c) {
            double xv = (double)xrow[c];
#pragma unroll
            for (int oc = 0; oc < SW; ++oc)
                a[oc] = fma(xv, (double)sW[c * SW + oc], a[oc]);
        }
        double ds = dg[s];
#pragma unroll
        for (int oc = 0; oc < SW; ++oc)
            hd2[oc * HP + s] = a[oc] * ds;
    }
    if (tid < SW) hd2[tid * HP + N_] = -0.0;   // sentinel
    __syncthreads();

    int oc = tid & 7, grp = tid >> 3;   // 64 node-groups x 8 channels
    const double* hrow = hd2 + oc * HP;
    const unsigned int* ssrc32 = (const unsigned int*)ssrc;
    double b = (double)bias[st * SW + oc];

    int nn[8], e0h[8], e1h[8];
    double a[8];
    int mx = 0;
#pragma unroll
    for (int j = 0; j < 8; ++j) {
        int n = sperm[grp * 8 + j];
        nn[j] = n;
        e0h[j] = sstart[n] >> 1;
        e1h[j] = sstart[n + 1] >> 1;
        a[j] = 0.0;
        int d = e1h[j] - e0h[j];
        mx = d > mx ? d : mx;
    }
    for (int t = 0; t < mx; ++t) {
#pragma unroll
        for (int j = 0; j < 8; ++j) {
            int idx = e0h[j] + t;
            if (idx < e1h[j]) {
                unsigned int pr = ssrc32[idx];
                a[j] += hrow[pr & 0xFFFFu];
                a[j] += hrow[pr >> 16];
            }
        }
    }
#pragma unroll
    for (int j = 0; j < 8; ++j) {
        int n = nn[j];
        double dn = dg[n];
        double v = a[j] * dn + hrow[n] * dn + b;
        xoutf[(nbase + n) * HID_ + st * SW + oc] = tanhf((float)v);
    }
}

// ---------------- fused layer-3 + head (one block per graph, 512 thr) ------
__global__ __launch_bounds__(512) void gcn3_head_kernel(
        const float* __restrict__ xin,      // x2f
        const float* __restrict__ W2,
        const float* __restrict__ b2,
        const unsigned short* __restrict__ srcl,
        const int* __restrict__ gstart,
        const double* __restrict__ disd,
        const float* __restrict__ x1,
        const float* __restrict__ x2,
        const float* __restrict__ c1w, const float* __restrict__ c1b,
        const float* __restrict__ c2w, const float* __restrict__ c2b,
        const float* __restrict__ l1w, const float* __restrict__ l1b,
        const float* __restrict__ l2w, const float* __restrict__ l2b,
        float* __restrict__ out) {
    __shared__ double h1[N_ + 1];
    __shared__ unsigned short ssrc[EGP];
    __shared__ int sstart[N_ + 1];
    __shared__ double sdis[N_ + 1];
    __shared__ float sv[N_];
    __shared__ int   topk[K_];
    __shared__ float pooled[K_][LAT_];
    __shared__ float c1[16][K_];
    __shared__ float mp[16][10];
    __shared__ float c2s[32 * 6];
    __shared__ float l1s[128];
    int g = blockIdx.x, tid = threadIdx.x;
    size_t nbase = (size_t)g * N_;

    for (int i = tid; i < EGP; i += 512) ssrc[i] = srcl[(size_t)g * EGP + i];
    for (int i = tid; i <= N_; i += 512) sstart[i] = gstart[g * (N_ + 1) + i];
    if (tid == 0) { h1[N_] = -0.0; sdis[N_] = 1.0; }   // sentinel term: -0.0
    if (tid < K_) topk[tid] = tid;                      // fallback init
    int n = tid;
    {
        double a = 0.0;
#pragma unroll
        for (int c = 0; c < HID_; ++c)
            a = fma((double)xin[(nbase + n) * HID_ + c], (double)W2[c], a);
        h1[n] = a;
        sdis[n] = disd[nbase + n];
    }
    __syncthreads();

    {
        int e0 = sstart[n], e1 = sstart[n + 1];
        double a = 0.0;
        for (int e = e0; e < e1; ++e) {
            int s = ssrc[e];
            a += h1[s] * sdis[s];
        }
        double dn = sdis[n];
        double v = a * dn + h1[n] * dn * dn + (double)b2[0];
        sv[n] = (float)tanh(v);   // fp32 rank key AND feature value
    }
    __syncthreads();

    {
        float v = sv[n];
        int rank = 0;
        for (int j = 0; j < N_; ++j) {
            float u = sv[j];
            float mag = fmaxf(fabsf(u), fabsf(v));
            bool tie = fabsf(u - v) <= EPS_REL * mag;
            bool beats = tie ? (j < n) : (u > v);
            rank += beats;
        }
        if (rank < K_) topk[rank] = n;
    }
    __syncthreads();

    for (int i = tid; i < K_ * LAT_; i += 512) {
        int k = i / LAT_, c = i % LAT_;
        int node = topk[k];
        float f;
        if (c < HID_)            f = x1[(nbase + node) * HID_ + c];
        else if (c < 2 * HID_)   f = x2[(nbase + node) * HID_ + (c - HID_)];
        else                     f = sv[node];
        pooled[k][c] = f;
    }
    __syncthreads();

    for (int i = tid; i < 16 * K_; i += 512) {
        int o = i / K_, k = i % K_;
        float acc = c1b[o];
        for (int c = 0; c < LAT_; ++c) acc += pooled[k][c] * c1w[o * LAT_ + c];
        c1[o][k] = fmaxf(acc, 0.f);
    }
    __syncthreads();

    for (int i = tid; i < 160; i += 512) {
        int o = i / 10, t = i % 10;
        mp[o][t] = fmaxf(c1[o][2 * t], c1[o][2 * t + 1]);
    }
    __syncthreads();

    for (int i = tid; i < 192; i += 512) {
        int o = i / 6, t = i % 6;
        float acc = c2b[o];
        for (int ic = 0; ic < 16; ++ic)
#pragma unroll
            for (int j = 0; j < 5; ++j)
                acc += mp[ic][t + j] * c2w[(o * 16 + ic) * 5 + j];
        c2s[o * 6 + t] = fmaxf(acc, 0.f);
    }
    __syncthreads();

    for (int i = tid; i < 128; i += 512) {
        float acc = l1b[i];
        for (int c = 0; c < 192; ++c) acc += c2s[c] * l1w[c * 128 + i];
        l1s[i] = fmaxf(acc, 0.f);
    }
    __syncthreads();

    for (int i = tid; i < 2; i += 512) {
        float acc = l2b[i];
        for (int c = 0; c < 128; ++c) acc += l1s[c] * l2w[c * 2 + i];
        out[g * 2 + i] = acc;
    }
}

extern "C" void kernel_launch(void* const* d_in, const int* in_sizes, int n_in,
                              void* d_out, int out_size, void* d_ws, size_t ws_size,
                              hipStream_t stream) {
    const float* x   = (const float*)d_in[0];
    const int*   ei  = (const int*)d_in[1];
    const float* W0  = (const float*)d_in[3];
    const float* b0  = (const float*)d_in[4];
    const float* W1  = (const float*)d_in[5];
    const float* b1  = (const float*)d_in[6];
    const float* W2  = (const float*)d_in[7];
    const float* b2  = (const float*)d_in[8];
    const float* c1w = (const float*)d_in[9];
    const float* c1b = (const float*)d_in[10];
    const float* c2w = (const float*)d_in[11];
    const float* c2b = (const float*)d_in[12];
    const float* l1w = (const float*)d_in[13];
    const float* l1b = (const float*)d_in[14];
    const float* l2w = (const float*)d_in[15];
    const float* l2b = (const float*)d_in[16];

    const int* src = ei;
    const int* dst = ei + (size_t)G_ * EG_;

    char* wsb = (char*)d_ws;
    double* h64  = (double*)wsb;                 wsb += (size_t)NN_ * HID_ * 8;     // 64 MiB (stripe-major)
    unsigned short* srcl = (unsigned short*)wsb; wsb += (size_t)G_ * EGP * 2;       // 8.5 MiB
    int* gstart = (int*)wsb;                     wsb += (size_t)G_ * (N_ + 1) * 4;  // 1 MiB
    unsigned short* nperm = (unsigned short*)wsb; wsb += (size_t)G_ * N_ * 2;       // 0.5 MiB
    double* disd = (double*)wsb;                 wsb += (size_t)NN_ * 8;            // 2 MiB
    float*  x1f  = (float*)wsb;                  wsb += (size_t)NN_ * HID_ * 4;     // 32 MiB
    float*  x2f  = (float*)wsb;                  wsb += (size_t)NN_ * HID_ * 4;     // 32 MiB

    dim3 agrid(G_, NSTRIPE);
    csr2_kernel<<<G_, 512, 0, stream>>>(src, dst, srcl, gstart, nperm, disd);
    mm_kernel<CIN_><<<NN_ / 64, 256, 0, stream>>>(x, W0, h64);
    agg_kernel<<<agrid, 512, 0, stream>>>(h64, srcl, gstart, nperm, disd, b0, x1f);
    agg_mm_kernel<<<agrid, 512, 0, stream>>>(x1f, W1, srcl, gstart, nperm, disd, b1, x2f);
    gcn3_head_kernel<<<G_, 512, 0, stream>>>(x2f, W2, b2, srcl, gstart, disd,
                                             x1f, x2f, c1w, c1b, c2w, c2b,
                                             l1w, l1b, l2w, l2b, (float*)d_out);
}